// Round 16
// baseline (158.913 us; speedup 1.0000x reference)
//
#include <hip/hip_runtime.h>
#include <math.h>

#define NN 100000   // nodes
#define NE 640000   // edges
#define DF 128      // in/hidden feat
#define DOUT 40     // out feat
#define D2 48       // padded W2 cols
#define DEGS 16     // deg padded to one counter per 64B line

typedef short bf16x8 __attribute__((ext_vector_type(8)));
typedef float f32x4 __attribute__((ext_vector_type(4)));
typedef float f32x2 __attribute__((ext_vector_type(2)));

#if defined(__has_builtin)
#if __has_builtin(__builtin_amdgcn_cvt_pk_f32_fp8) && __has_builtin(__builtin_amdgcn_cvt_pk_fp8_f32)
#define HW_FP8 1
#endif
#endif
#ifndef HW_FP8
#define HW_FP8 0
#endif

__device__ __forceinline__ unsigned short f2bf(float f) {
    unsigned int u = __float_as_uint(f);
    u += 0x7fffu + ((u >> 16) & 1u);   // RNE
    return (unsigned short)(u >> 16);
}

__device__ __forceinline__ unsigned int f2fp8_manual(float f) {
    unsigned u = __float_as_uint(f);
    unsigned s = (u >> 24) & 0x80u;
    unsigned au = u & 0x7fffffffu;
    if (au > 0x43e00000u) au = 0x43e00000u;   // clamp |x| to 448
    au += 0x7ffffu + ((au >> 20) & 1u);       // RNE to 3-bit mantissa
    if (au < 0x3c800000u) return s;           // flush < 2^-6 to 0
    unsigned e = (au >> 23) - 120u;
    return s | (e << 3) | ((au >> 20) & 7u);
}

__device__ __forceinline__ unsigned short f2fp8x2(float x, float y) {
#if HW_FP8
    int v = __builtin_amdgcn_cvt_pk_fp8_f32(x, y, 0, false);
    return (unsigned short)(v & 0xffff);
#else
    return (unsigned short)(f2fp8_manual(x) | (f2fp8_manual(y) << 8));
#endif
}

__device__ __forceinline__ void fp8pair(unsigned short p, float& x, float& y) {
#if HW_FP8
    f32x2 r = __builtin_amdgcn_cvt_pk_f32_fp8((int)(unsigned)p, false);
    x = r.x; y = r.y;
#else
    unsigned lo = p & 0xffu, hi = (p >> 8) & 0xffu;
    x = __uint_as_float(((lo & 0x80u) << 24) | ((lo & 0x7fu) << 20)) * 0x1.0p120f;
    y = __uint_as_float(((hi & 0x80u) << 24) | ((hi & 0x7fu) << 20)) * 0x1.0p120f;
#endif
}

// decode 4 packed fp8 from one uint (lo word -> x0,y0; hi word -> x1,y1)
__device__ __forceinline__ void fp8quad(unsigned int q, float& x0, float& y0,
                                        float& x1, float& y1) {
#if HW_FP8
    f32x2 lo = __builtin_amdgcn_cvt_pk_f32_fp8((int)q, false);
    f32x2 hi = __builtin_amdgcn_cvt_pk_f32_fp8((int)q, true);
    x0 = lo.x; y0 = lo.y; x1 = hi.x; y1 = hi.y;
#else
    fp8pair((unsigned short)(q & 0xffffu), x0, y0);
    fp8pair((unsigned short)(q >> 16), x1, y1);
#endif
}

// ---------------- K1: zero padded deg (NN*DEGS ints) ----------------
__global__ __launch_bounds__(256) void zero_deg_kernel(int* __restrict__ deg) {
    int i = blockIdx.x * 256 + threadIdx.x;
    if (i < NN * DEGS) deg[i] = 0;
}

// ---------------- K2: mega — hist || convert-x (bf16+fp8) || pack W1/W2 ----
// hist range FIRST so its atomic latency overlaps conv's streaming BW.
#define MK_HIST 2500
#define MK_CONV (MK_HIST + 6250)
#define MK_W1   (MK_CONV + 16)
#define MK_W2   (MK_W1 + 6)
#define MK_GRID MK_W2

__global__ __launch_bounds__(256) void mega_kernel(const float* __restrict__ x,
                                                   unsigned short* __restrict__ xb,
                                                   unsigned char* __restrict__ xq,
                                                   const float* __restrict__ W1l,
                                                   const float* __restrict__ W1r,
                                                   unsigned short* __restrict__ w1p,
                                                   const float* __restrict__ W2l,
                                                   const float* __restrict__ W2r,
                                                   unsigned short* __restrict__ w2lp,
                                                   unsigned short* __restrict__ w2rp,
                                                   const int* __restrict__ dst,
                                                   int* __restrict__ deg,
                                                   int* __restrict__ rank) {
    const int bid = blockIdx.x;
    const int tid = threadIdx.x;
    if (bid < MK_HIST) {
        int e = bid * 256 + tid;
        if (e < NE) rank[e] = atomicAdd(&deg[(size_t)dst[e] * DEGS], 1);
    } else if (bid < MK_CONV) {
        int i = ((bid - MK_HIST) * 256 + tid) * 8;
        float4 a = *reinterpret_cast<const float4*>(x + i);
        float4 b = *reinterpret_cast<const float4*>(x + i + 4);
        uint4 o;
        o.x = (unsigned)f2bf(a.x) | ((unsigned)f2bf(a.y) << 16);
        o.y = (unsigned)f2bf(a.z) | ((unsigned)f2bf(a.w) << 16);
        o.z = (unsigned)f2bf(b.x) | ((unsigned)f2bf(b.y) << 16);
        o.w = (unsigned)f2bf(b.z) | ((unsigned)f2bf(b.w) << 16);
        *reinterpret_cast<uint4*>(xb + (size_t)i) = o;
        unsigned short q0 = f2fp8x2(a.x, a.y);
        unsigned short q1 = f2fp8x2(a.z, a.w);
        unsigned short q2 = f2fp8x2(b.x, b.y);
        unsigned short q3 = f2fp8x2(b.z, b.w);
        uint2 qo;
        qo.x = (unsigned)q0 | ((unsigned)q1 << 16);
        qo.y = (unsigned)q2 | ((unsigned)q3 << 16);
        *reinterpret_cast<uint2*>(xq + (size_t)i) = qo;
    } else if (bid < MK_W1) {
        // B-frag: lane holds B[k=(lane>>4)*8+j][col=ct*16+(lane&15)]
        int t = (bid - MK_CONV) * 256 + tid;     // 4096 = 8kt * 8ct * 64
        int lane = t & 63;
        int ct = (t >> 6) & 7;
        int kt = t >> 9;
        int c  = ct * 16 + (lane & 15);
        int k0 = (kt & 3) * 32 + (lane >> 4) * 8;
        const float* W = (kt < 4) ? W1l : W1r;
        unsigned int o[4];
#pragma unroll
        for (int j = 0; j < 4; ++j) {
            unsigned int lo = f2bf(W[(size_t)(k0 + 2 * j) * DF + c]);
            unsigned int hi = f2bf(W[(size_t)(k0 + 2 * j + 1) * DF + c]);
            o[j] = lo | (hi << 16);
        }
        uint4 v; v.x = o[0]; v.y = o[1]; v.z = o[2]; v.w = o[3];
        *reinterpret_cast<uint4*>(w1p + (size_t)t * 8) = v;
    } else {
        int t = (bid - MK_W1) * 256 + tid;       // 1536 = 2 * 4kt * 3ct * 64
        if (t < 1536) {
            int lane = t & 63;
            int g  = t >> 6;       // 0..23
            int ct = g % 3;
            int kt = g / 3;        // <4 -> W2l else W2r
            int c  = ct * 16 + (lane & 15);
            int k0 = (kt & 3) * 32 + (lane >> 4) * 8;
            const float* W = (kt < 4) ? W2l : W2r;
            unsigned short* dstp = (kt < 4) ? w2lp : w2rp;
            int slot = ((kt & 3) * 3 + ct) * 64 + lane;
            unsigned int o[4];
#pragma unroll
            for (int j = 0; j < 4; ++j) {
                unsigned int lo = (c < DOUT) ? f2bf(W[(size_t)(k0 + 2 * j) * DOUT + c]) : 0u;
                unsigned int hi = (c < DOUT) ? f2bf(W[(size_t)(k0 + 2 * j + 1) * DOUT + c]) : 0u;
                o[j] = lo | (hi << 16);
            }
            uint4 v; v.x = o[0]; v.y = o[1]; v.z = o[2]; v.w = o[3];
            *reinterpret_cast<uint4*>(dstp + (size_t)slot * 8) = v;
        }
    }
}

// ---------------- CSR build (scan + finalize + fill) ----------------

__global__ __launch_bounds__(256) void scan_block_kernel(const int* __restrict__ deg,
                                                         int* __restrict__ loc,
                                                         int* __restrict__ part) {
    __shared__ int tmp[256];
    const int t = threadIdx.x;
    const int i = blockIdx.x * 256 + t;
    int v = (i < NN) ? deg[(size_t)i * DEGS] : 0;
    tmp[t] = v;
    __syncthreads();
    for (int off = 1; off < 256; off <<= 1) {
        int a = (t >= off) ? tmp[t - off] : 0;
        __syncthreads();
        tmp[t] += a;
        __syncthreads();
    }
    if (i < NN) loc[i] = tmp[t] - v;
    if (t == 255) part[blockIdx.x] = tmp[t];
}

// fused small-scan + finalize: ofs2[i] = {start, start+deg}
__global__ __launch_bounds__(256) void add_off_kernel(const int* __restrict__ loc,
                                                      const int* __restrict__ part,
                                                      const int* __restrict__ deg,
                                                      int2* __restrict__ ofs2) {
    __shared__ int wsum[4];
    const int bb = blockIdx.x;
    const int t  = threadIdx.x;
    int psum = 0;
    for (int i = t; i < bb; i += 256) psum += part[i];
#pragma unroll
    for (int off = 32; off > 0; off >>= 1) psum += __shfl_down(psum, off);
    if ((t & 63) == 0) wsum[t >> 6] = psum;
    __syncthreads();
    int base = wsum[0] + wsum[1] + wsum[2] + wsum[3];
    int i = bb * 256 + t;
    if (i < NN) {
        int o = loc[i] + base;
        ofs2[i] = make_int2(o, o + deg[(size_t)i * DEGS]);
    }
}

__global__ __launch_bounds__(256) void fill_kernel(const int* __restrict__ src,
                                                   const int* __restrict__ dst,
                                                   const int2* __restrict__ ofs2,
                                                   const int* __restrict__ rank,
                                                   int* __restrict__ srcs) {
    int e = blockIdx.x * blockDim.x + threadIdx.x;
    if (e < NE) {
        int d = dst[e];
        __builtin_nontemporal_store(src[e], &srcs[ofs2[d].x + rank[e]]);
    }
}

// ---------------- gather-mean, 128-dim fp8 in -> bf16 out ------------------
// 2 nodes per wave: each 32-lane half owns one node; lane holds 4 fp8 dims
// (one 4B load per edge, decoded via packed cvt hi/lo words).
__global__ __launch_bounds__(256) void gather_mean_fp8_kernel(const unsigned char* __restrict__ xq,
                                                              const int2* __restrict__ ofs2,
                                                              const int* __restrict__ srcs,
                                                              unsigned short* __restrict__ agg) {
    const int gid    = blockIdx.x * 256 + threadIdx.x;
    const int node   = gid >> 5;               // 2 nodes per wave
    const int lane32 = threadIdx.x & 31;
    if (node >= NN) return;
    const int2 be = ofs2[node];
    const int b = be.x;
    const int e = be.y;
    const unsigned char* fp = xq + lane32 * 4;

    float a0 = 0.f, a1 = 0.f, a2 = 0.f, a3 = 0.f;
    float c0 = 0.f, c1 = 0.f, c2 = 0.f, c3 = 0.f;

    for (int j = b; j < e; j += 8) {
        int s[8];
#pragma unroll
        for (int k = 0; k < 8; ++k)
            s[k] = (j + k < e) ? srcs[j + k] : -1;
        unsigned int v[8];
#pragma unroll
        for (int k = 0; k < 8; ++k)
            v[k] = ((unsigned)s[k] < (unsigned)NN)
                 ? *reinterpret_cast<const unsigned int*>(fp + (size_t)s[k] * DF) : 0u;
        float x0, y0, x1, y1;
        fp8quad(v[0], x0, y0, x1, y1); a0 += x0; a1 += y0; a2 += x1; a3 += y1;
        fp8quad(v[1], x0, y0, x1, y1); c0 += x0; c1 += y0; c2 += x1; c3 += y1;
        fp8quad(v[2], x0, y0, x1, y1); a0 += x0; a1 += y0; a2 += x1; a3 += y1;
        fp8quad(v[3], x0, y0, x1, y1); c0 += x0; c1 += y0; c2 += x1; c3 += y1;
        fp8quad(v[4], x0, y0, x1, y1); a0 += x0; a1 += y0; a2 += x1; a3 += y1;
        fp8quad(v[5], x0, y0, x1, y1); c0 += x0; c1 += y0; c2 += x1; c3 += y1;
        fp8quad(v[6], x0, y0, x1, y1); a0 += x0; a1 += y0; a2 += x1; a3 += y1;
        fp8quad(v[7], x0, y0, x1, y1); c0 += x0; c1 += y0; c2 += x1; c3 += y1;
    }

    const float sc = 1.0f / fmaxf((float)(e - b), 1.0f);
    float s0 = (a0 + c0) * sc, s1 = (a1 + c1) * sc;
    float s2 = (a2 + c2) * sc, s3 = (a3 + c3) * sc;
    uint2 o;
    o.x = (unsigned)f2bf(s0) | ((unsigned)f2bf(s1) << 16);
    o.y = (unsigned)f2bf(s2) | ((unsigned)f2bf(s3) << 16);
    *reinterpret_cast<uint2*>(agg + (size_t)node * DF + lane32 * 4) = o;
}

// ---------------- MFMA GEMM (layer 1 + both layer-2 projections) -----------
// A-frag: lane holds A[row = lane&15][k = (lane>>4)*8 + j]
#define G_ROWS 64
#define LDSW 136

__global__ __launch_bounds__(256) void gemm1_kernel(const unsigned short* __restrict__ aggb,
                                                    const unsigned short* __restrict__ xb,
                                                    const unsigned short* __restrict__ w1p,
                                                    const unsigned short* __restrict__ w2lp,
                                                    const unsigned short* __restrict__ w2rp,
                                                    const float* __restrict__ b1,
                                                    const float* __restrict__ b2,
                                                    unsigned short* __restrict__ h2b,
                                                    unsigned short* __restrict__ h2rb) {
    __shared__ unsigned short sA[G_ROWS * LDSW];
    __shared__ unsigned short sX[G_ROWS * LDSW];
    const int t = threadIdx.x;
    const int row0 = blockIdx.x * G_ROWS;

    for (int i = t; i < G_ROWS * 16; i += 256) {
        int r = i >> 4, ch = i & 15;
        int sr = row0 + r; if (sr > NN - 1) sr = NN - 1;
        *reinterpret_cast<uint4*>(&sA[r * LDSW + ch * 8]) =
            *reinterpret_cast<const uint4*>(aggb + (size_t)sr * DF + ch * 8);
        *reinterpret_cast<uint4*>(&sX[r * LDSW + ch * 8]) =
            *reinterpret_cast<const uint4*>(xb + (size_t)sr * DF + ch * 8);
    }
    __syncthreads();

    const int lane = t & 63;
    const int w = t >> 6;
    const int lr = lane & 15;
    const int hi = lane >> 4;
    f32x4 acc[8];
#pragma unroll
    for (int i = 0; i < 8; ++i) acc[i] = (f32x4){0.f, 0.f, 0.f, 0.f};

    const int arow = (w * 16 + lr) * LDSW + hi * 8;
#pragma unroll
    for (int half = 0; half < 2; ++half) {
        const unsigned short* base = half ? sX : sA;
#pragma unroll
        for (int kq = 0; kq < 4; ++kq) {
            bf16x8 a = __builtin_bit_cast(bf16x8,
                *reinterpret_cast<const uint4*>(&base[arow + kq * 32]));
            const unsigned short* wp = w1p + (size_t)(((half * 4 + kq) * 8) * 64 + lane) * 8;
#pragma unroll
            for (int ct = 0; ct < 8; ++ct) {
                bf16x8 b = __builtin_bit_cast(bf16x8,
                    *reinterpret_cast<const uint4*>(wp + ct * 512));
                acc[ct] = __builtin_amdgcn_mfma_f32_16x16x32_bf16(a, b, acc[ct], 0, 0, 0);
            }
        }
    }

    // relu + bias -> bf16 registers
    unsigned short hreg[8][4];
#pragma unroll
    for (int ct = 0; ct < 8; ++ct) {
        float bias = b1[ct * 16 + lr];
#pragma unroll
        for (int v = 0; v < 4; ++v) {
            hreg[ct][v] = f2bf(fmaxf(acc[ct][v] + bias, 0.f));
        }
    }

    __syncthreads();   // stage-1 LDS reads done before overwrite
#pragma unroll
    for (int ct = 0; ct < 8; ++ct) {
#pragma unroll
        for (int v = 0; v < 4; ++v) {
            sA[(w * 16 + hi * 4 + v) * LDSW + ct * 16 + lr] = hreg[ct][v];
        }
    }
    __syncthreads();

    // stages 2+3: h @ W2l and h @ W2r + b2 (48 padded cols each)
    f32x4 acc2[3], acc3[3];
#pragma unroll
    for (int i = 0; i < 3; ++i) {
        acc2[i] = (f32x4){0.f, 0.f, 0.f, 0.f};
        acc3[i] = (f32x4){0.f, 0.f, 0.f, 0.f};
    }
#pragma unroll
    for (int kq = 0; kq < 4; ++kq) {
        bf16x8 a = __builtin_bit_cast(bf16x8,
            *reinterpret_cast<const uint4*>(&sA[arow + kq * 32]));
        const unsigned short* wpl = w2lp + (size_t)((kq * 3) * 64 + lane) * 8;
        const unsigned short* wpr = w2rp + (size_t)((kq * 3) * 64 + lane) * 8;
#pragma unroll
        for (int ct = 0; ct < 3; ++ct) {
            bf16x8 bl = __builtin_bit_cast(bf16x8,
                *reinterpret_cast<const uint4*>(wpl + ct * 512));
            bf16x8 br = __builtin_bit_cast(bf16x8,
                *reinterpret_cast<const uint4*>(wpr + ct * 512));
            acc2[ct] = __builtin_amdgcn_mfma_f32_16x16x32_bf16(a, bl, acc2[ct], 0, 0, 0);
            acc3[ct] = __builtin_amdgcn_mfma_f32_16x16x32_bf16(a, br, acc3[ct], 0, 0, 0);
        }
    }
#pragma unroll
    for (int ct = 0; ct < 3; ++ct) {
        int col = ct * 16 + lr;
        float bias2 = (col < DOUT) ? b2[col] : 0.f;
#pragma unroll
        for (int v = 0; v < 4; ++v) {
            int row = row0 + w * 16 + hi * 4 + v;
            if (row < NN) {
                h2b[(size_t)row * D2 + col]  = f2bf(acc2[ct][v]);
                h2rb[(size_t)row * D2 + col] = f2bf(acc3[ct][v] + bias2);
            }
        }
    }
}

// ---------------- fused gather48 + log_softmax, 2 nodes per wave -----------
// each 32-lane half handles one node; lanes 0..19 of the half hold col pair
// {2l, 2l+1}. xor-shuffle reduce (offsets 16..1) stays within the half.
__global__ __launch_bounds__(256) void gather_finish_kernel(const unsigned short* __restrict__ h2b,
                                                            const unsigned short* __restrict__ h2rb,
                                                            const int2* __restrict__ ofs2,
                                                            const int* __restrict__ srcs,
                                                            float* __restrict__ out) {
    const int gid   = blockIdx.x * 256 + threadIdx.x;
    const int node  = gid >> 5;                 // 2 nodes per wave
    const int lane32 = threadIdx.x & 31;
    if (node >= NN) return;
    const int2 be = ofs2[node];
    const int b = be.x;
    const int e = be.y;
    const bool act = lane32 < 20;
    const unsigned short* fp = h2b + lane32 * 2;

    float ax0 = 0.f, ay0 = 0.f, ax1 = 0.f, ay1 = 0.f;
    float ax2 = 0.f, ay2 = 0.f, ax3 = 0.f, ay3 = 0.f;

    for (int j = b; j < e; j += 8) {
        int s[8];
#pragma unroll
        for (int k = 0; k < 8; ++k)
            s[k] = (j + k < e) ? srcs[j + k] : -1;
        unsigned int v[8];
#pragma unroll
        for (int k = 0; k < 8; ++k)
            v[k] = (act && (unsigned)s[k] < (unsigned)NN)
                 ? *reinterpret_cast<const unsigned int*>(fp + (size_t)s[k] * D2) : 0u;
        ax0 += __uint_as_float(v[0] << 16);  ay0 += __uint_as_float(v[0] & 0xffff0000u);
        ax1 += __uint_as_float(v[1] << 16);  ay1 += __uint_as_float(v[1] & 0xffff0000u);
        ax2 += __uint_as_float(v[2] << 16);  ay2 += __uint_as_float(v[2] & 0xffff0000u);
        ax3 += __uint_as_float(v[3] << 16);  ay3 += __uint_as_float(v[3] & 0xffff0000u);
        ax0 += __uint_as_float(v[4] << 16);  ay0 += __uint_as_float(v[4] & 0xffff0000u);
        ax1 += __uint_as_float(v[5] << 16);  ay1 += __uint_as_float(v[5] & 0xffff0000u);
        ax2 += __uint_as_float(v[6] << 16);  ay2 += __uint_as_float(v[6] & 0xffff0000u);
        ax3 += __uint_as_float(v[7] << 16);  ay3 += __uint_as_float(v[7] & 0xffff0000u);
    }

    const float sc = 1.0f / fmaxf((float)(e - b), 1.0f);
    float a0 = ((ax0 + ax1) + (ax2 + ax3)) * sc;
    float a1 = ((ay0 + ay1) + (ay2 + ay3)) * sc;

    float lv0 = -INFINITY, lv1 = -INFINITY;
    if (act) {
        unsigned int sv = *reinterpret_cast<const unsigned int*>(h2rb + (size_t)node * D2 + lane32 * 2);
        lv0 = a0 + __uint_as_float(sv << 16);
        lv1 = a1 + __uint_as_float(sv & 0xffff0000u);
    }

    float mx = fmaxf(lv0, lv1);
#pragma unroll
    for (int off = 16; off > 0; off >>= 1) mx = fmaxf(mx, __shfl_xor(mx, off));
    float e0 = act ? __expf(lv0 - mx) : 0.f;
    float e1 = act ? __expf(lv1 - mx) : 0.f;
    float s = e0 + e1;
#pragma unroll
    for (int off = 16; off > 0; off >>= 1) s += __shfl_xor(s, off);
    float lz = mx + __logf(s);
    if (act) {
        float2 o = make_float2(lv0 - lz, lv1 - lz);
        *reinterpret_cast<float2*>(out + (size_t)node * DOUT + lane32 * 2) = o;
    }
}

extern "C" void kernel_launch(void* const* d_in, const int* in_sizes, int n_in,
                              void* d_out, int out_size, void* d_ws, size_t ws_size,
                              hipStream_t stream) {
    const float* x   = (const float*)d_in[0];
    const int*   ei  = (const int*)d_in[1];
    const int*   src = ei;
    const int*   dst = ei + NE;
    const float* W1l = (const float*)d_in[2];
    const float* W1r = (const float*)d_in[3];
    const float* b1  = (const float*)d_in[4];
    const float* W2l = (const float*)d_in[5];
    const float* W2r = (const float*)d_in[6];
    const float* b2  = (const float*)d_in[7];
    float* out = (float*)d_out;

    int* ip    = (int*)d_ws;
    int* deg   = ip;              // NN*DEGS = 1,600,000 (64B-padded counters)
    int* loc   = ip + 1600000;    // 100000
    int* rank  = ip + 1700000;    // 640000
    int* srcs  = ip + 2340000;    // 640008
    int* part  = ip + 2980008;    // 512
    int2* ofs2 = (int2*)(ip + 2980520);  // 100000 int2, 8B aligned
    unsigned short* up    = (unsigned short*)(ip + 3180520);  // 16B aligned
    unsigned short* xb    = up;                   // NN*DF = 12,800,000
    unsigned short* aggb  = up + 12800000;        // NN*DF
    unsigned short* h2b   = up + 25600000;        // NN*48 = 4,800,000
    unsigned short* h2rb  = up + 30400000;        // NN*48
    unsigned short* w1p   = up + 35200000;        // 32768
    unsigned short* w2lp  = up + 35232768;        // 6144
    unsigned short* w2rp  = up + 35238912;        // 6144
    unsigned char*  xq    = (unsigned char*)(up + 35245056);  // NN*DF bytes

    zero_deg_kernel<<<(NN * DEGS + 255) / 256, 256, 0, stream>>>(deg);
    mega_kernel<<<MK_GRID, 256, 0, stream>>>(x, xb, xq, W1l, W1r, w1p,
                                             W2l, W2r, w2lp, w2rp, dst, deg, rank);

    scan_block_kernel<<<391, 256, 0, stream>>>(deg, loc, part);
    add_off_kernel<<<391, 256, 0, stream>>>(loc, part, deg, ofs2);
    fill_kernel<<<(NE + 255) / 256, 256, 0, stream>>>(src, dst, ofs2, rank, srcs);

    gather_mean_fp8_kernel<<<12500, 256, 0, stream>>>(xq, ofs2, srcs, aggb);
    gemm1_kernel<<<1563, 256, 0, stream>>>(aggb, xb, w1p, w2lp, w2rp, b1, b2, h2b, h2rb);
    gather_finish_kernel<<<12500, 256, 0, stream>>>(h2b, h2rb, ofs2, srcs, out);
}

// Round 17
// 148.088 us; speedup vs baseline: 1.0731x; 1.0731x over previous
//
#include <hip/hip_runtime.h>
#include <math.h>

#define NN 100000   // nodes
#define NE 640000   // edges
#define DF 128      // in/hidden feat
#define DOUT 40     // out feat
#define D2 48       // padded W2 cols

typedef short bf16x8 __attribute__((ext_vector_type(8)));
typedef float f32x4 __attribute__((ext_vector_type(4)));
typedef float f32x2 __attribute__((ext_vector_type(2)));

#if defined(__has_builtin)
#if __has_builtin(__builtin_amdgcn_cvt_pk_f32_fp8) && __has_builtin(__builtin_amdgcn_cvt_pk_fp8_f32)
#define HW_FP8 1
#endif
#endif
#ifndef HW_FP8
#define HW_FP8 0
#endif

__device__ __forceinline__ unsigned short f2bf(float f) {
    unsigned int u = __float_as_uint(f);
    u += 0x7fffu + ((u >> 16) & 1u);   // RNE
    return (unsigned short)(u >> 16);
}

__device__ __forceinline__ unsigned int f2fp8_manual(float f) {
    unsigned u = __float_as_uint(f);
    unsigned s = (u >> 24) & 0x80u;
    unsigned au = u & 0x7fffffffu;
    if (au > 0x43e00000u) au = 0x43e00000u;   // clamp |x| to 448
    au += 0x7ffffu + ((au >> 20) & 1u);       // RNE to 3-bit mantissa
    if (au < 0x3c800000u) return s;           // flush < 2^-6 to 0
    unsigned e = (au >> 23) - 120u;
    return s | (e << 3) | ((au >> 20) & 7u);
}

__device__ __forceinline__ unsigned short f2fp8x2(float x, float y) {
#if HW_FP8
    int v = __builtin_amdgcn_cvt_pk_fp8_f32(x, y, 0, false);
    return (unsigned short)(v & 0xffff);
#else
    return (unsigned short)(f2fp8_manual(x) | (f2fp8_manual(y) << 8));
#endif
}

__device__ __forceinline__ void fp8pair(unsigned short p, float& x, float& y) {
#if HW_FP8
    f32x2 r = __builtin_amdgcn_cvt_pk_f32_fp8((int)(unsigned)p, false);
    x = r.x; y = r.y;
#else
    unsigned lo = p & 0xffu, hi = (p >> 8) & 0xffu;
    x = __uint_as_float(((lo & 0x80u) << 24) | ((lo & 0x7fu) << 20)) * 0x1.0p120f;
    y = __uint_as_float(((hi & 0x80u) << 24) | ((hi & 0x7fu) << 20)) * 0x1.0p120f;
#endif
}

// decode 4 packed fp8 from one uint (lo word -> x0,y0; hi word -> x1,y1)
__device__ __forceinline__ void fp8quad(unsigned int q, float& x0, float& y0,
                                        float& x1, float& y1) {
#if HW_FP8
    f32x2 lo = __builtin_amdgcn_cvt_pk_f32_fp8((int)q, false);
    f32x2 hi = __builtin_amdgcn_cvt_pk_f32_fp8((int)q, true);
    x0 = lo.x; y0 = lo.y; x1 = hi.x; y1 = hi.y;
#else
    fp8pair((unsigned short)(q & 0xffffu), x0, y0);
    fp8pair((unsigned short)(q >> 16), x1, y1);
#endif
}

// ---------------- K1: zero deg ----------------
__global__ __launch_bounds__(256) void zero_deg_kernel(int* __restrict__ deg) {
    int i = blockIdx.x * 256 + threadIdx.x;
    if (i < NN) deg[i] = 0;
}

// ---------------- K2: mega — hist || convert-x (bf16+fp8) || pack W1/W2 ----
// hist range FIRST so its atomic latency overlaps conv's streaming BW.
#define MK_HIST 2500
#define MK_CONV (MK_HIST + 6250)
#define MK_W1   (MK_CONV + 16)
#define MK_W2   (MK_W1 + 6)
#define MK_GRID MK_W2

__global__ __launch_bounds__(256) void mega_kernel(const float* __restrict__ x,
                                                   unsigned short* __restrict__ xb,
                                                   unsigned char* __restrict__ xq,
                                                   const float* __restrict__ W1l,
                                                   const float* __restrict__ W1r,
                                                   unsigned short* __restrict__ w1p,
                                                   const float* __restrict__ W2l,
                                                   const float* __restrict__ W2r,
                                                   unsigned short* __restrict__ w2lp,
                                                   unsigned short* __restrict__ w2rp,
                                                   const int* __restrict__ dst,
                                                   int* __restrict__ deg,
                                                   int* __restrict__ rank) {
    const int bid = blockIdx.x;
    const int tid = threadIdx.x;
    if (bid < MK_HIST) {
        int e = bid * 256 + tid;
        if (e < NE) rank[e] = atomicAdd(&deg[dst[e]], 1);
    } else if (bid < MK_CONV) {
        int i = ((bid - MK_HIST) * 256 + tid) * 8;
        float4 a = *reinterpret_cast<const float4*>(x + i);
        float4 b = *reinterpret_cast<const float4*>(x + i + 4);
        uint4 o;
        o.x = (unsigned)f2bf(a.x) | ((unsigned)f2bf(a.y) << 16);
        o.y = (unsigned)f2bf(a.z) | ((unsigned)f2bf(a.w) << 16);
        o.z = (unsigned)f2bf(b.x) | ((unsigned)f2bf(b.y) << 16);
        o.w = (unsigned)f2bf(b.z) | ((unsigned)f2bf(b.w) << 16);
        *reinterpret_cast<uint4*>(xb + (size_t)i) = o;
        unsigned short q0 = f2fp8x2(a.x, a.y);
        unsigned short q1 = f2fp8x2(a.z, a.w);
        unsigned short q2 = f2fp8x2(b.x, b.y);
        unsigned short q3 = f2fp8x2(b.z, b.w);
        uint2 qo;
        qo.x = (unsigned)q0 | ((unsigned)q1 << 16);
        qo.y = (unsigned)q2 | ((unsigned)q3 << 16);
        *reinterpret_cast<uint2*>(xq + (size_t)i) = qo;
    } else if (bid < MK_W1) {
        // B-frag: lane holds B[k=(lane>>4)*8+j][col=ct*16+(lane&15)]
        int t = (bid - MK_CONV) * 256 + tid;     // 4096 = 8kt * 8ct * 64
        int lane = t & 63;
        int ct = (t >> 6) & 7;
        int kt = t >> 9;
        int c  = ct * 16 + (lane & 15);
        int k0 = (kt & 3) * 32 + (lane >> 4) * 8;
        const float* W = (kt < 4) ? W1l : W1r;
        unsigned int o[4];
#pragma unroll
        for (int j = 0; j < 4; ++j) {
            unsigned int lo = f2bf(W[(size_t)(k0 + 2 * j) * DF + c]);
            unsigned int hi = f2bf(W[(size_t)(k0 + 2 * j + 1) * DF + c]);
            o[j] = lo | (hi << 16);
        }
        uint4 v; v.x = o[0]; v.y = o[1]; v.z = o[2]; v.w = o[3];
        *reinterpret_cast<uint4*>(w1p + (size_t)t * 8) = v;
    } else {
        int t = (bid - MK_W1) * 256 + tid;       // 1536 = 2 * 4kt * 3ct * 64
        if (t < 1536) {
            int lane = t & 63;
            int g  = t >> 6;       // 0..23
            int ct = g % 3;
            int kt = g / 3;        // <4 -> W2l else W2r
            int c  = ct * 16 + (lane & 15);
            int k0 = (kt & 3) * 32 + (lane >> 4) * 8;
            const float* W = (kt < 4) ? W2l : W2r;
            unsigned short* dstp = (kt < 4) ? w2lp : w2rp;
            int slot = ((kt & 3) * 3 + ct) * 64 + lane;
            unsigned int o[4];
#pragma unroll
            for (int j = 0; j < 4; ++j) {
                unsigned int lo = (c < DOUT) ? f2bf(W[(size_t)(k0 + 2 * j) * DOUT + c]) : 0u;
                unsigned int hi = (c < DOUT) ? f2bf(W[(size_t)(k0 + 2 * j + 1) * DOUT + c]) : 0u;
                o[j] = lo | (hi << 16);
            }
            uint4 v; v.x = o[0]; v.y = o[1]; v.z = o[2]; v.w = o[3];
            *reinterpret_cast<uint4*>(dstp + (size_t)slot * 8) = v;
        }
    }
}

// ---------------- CSR build (scan + finalize + fill) ----------------

__global__ __launch_bounds__(256) void scan_block_kernel(const int* __restrict__ deg,
                                                         int* __restrict__ loc,
                                                         int* __restrict__ part) {
    __shared__ int tmp[256];
    const int t = threadIdx.x;
    const int i = blockIdx.x * 256 + t;
    int v = (i < NN) ? deg[i] : 0;
    tmp[t] = v;
    __syncthreads();
    for (int off = 1; off < 256; off <<= 1) {
        int a = (t >= off) ? tmp[t - off] : 0;
        __syncthreads();
        tmp[t] += a;
        __syncthreads();
    }
    if (i < NN) loc[i] = tmp[t] - v;
    if (t == 255) part[blockIdx.x] = tmp[t];
}

// fused small-scan + finalize: ofs2[i] = {start, start+deg}
__global__ __launch_bounds__(256) void add_off_kernel(const int* __restrict__ loc,
                                                      const int* __restrict__ part,
                                                      const int* __restrict__ deg,
                                                      int2* __restrict__ ofs2) {
    __shared__ int wsum[4];
    const int bb = blockIdx.x;
    const int t  = threadIdx.x;
    int psum = 0;
    for (int i = t; i < bb; i += 256) psum += part[i];
#pragma unroll
    for (int off = 32; off > 0; off >>= 1) psum += __shfl_down(psum, off);
    if ((t & 63) == 0) wsum[t >> 6] = psum;
    __syncthreads();
    int base = wsum[0] + wsum[1] + wsum[2] + wsum[3];
    int i = bb * 256 + t;
    if (i < NN) {
        int o = loc[i] + base;
        ofs2[i] = make_int2(o, o + deg[i]);
    }
}

__global__ __launch_bounds__(256) void fill_kernel(const int* __restrict__ src,
                                                   const int* __restrict__ dst,
                                                   const int2* __restrict__ ofs2,
                                                   const int* __restrict__ rank,
                                                   int* __restrict__ srcs) {
    int e = blockIdx.x * blockDim.x + threadIdx.x;
    if (e < NE) {
        int d = dst[e];
        srcs[ofs2[d].x + rank[e]] = src[e];
    }
}

// ---------------- gather-mean, 128-dim fp8 in -> bf16 out ------------------
// 2 nodes per wave: each 32-lane half owns one node; lane holds 4 fp8 dims
// (one 4B load per edge, decoded via packed cvt hi/lo words).
__global__ __launch_bounds__(256) void gather_mean_fp8_kernel(const unsigned char* __restrict__ xq,
                                                              const int2* __restrict__ ofs2,
                                                              const int* __restrict__ srcs,
                                                              unsigned short* __restrict__ agg) {
    const int gid    = blockIdx.x * 256 + threadIdx.x;
    const int node   = gid >> 5;               // 2 nodes per wave
    const int lane32 = threadIdx.x & 31;
    if (node >= NN) return;
    const int2 be = ofs2[node];
    const int b = be.x;
    const int e = be.y;
    const unsigned char* fp = xq + lane32 * 4;

    float a0 = 0.f, a1 = 0.f, a2 = 0.f, a3 = 0.f;
    float c0 = 0.f, c1 = 0.f, c2 = 0.f, c3 = 0.f;

    for (int j = b; j < e; j += 8) {
        int s[8];
#pragma unroll
        for (int k = 0; k < 8; ++k)
            s[k] = (j + k < e) ? srcs[j + k] : -1;
        unsigned int v[8];
#pragma unroll
        for (int k = 0; k < 8; ++k)
            v[k] = ((unsigned)s[k] < (unsigned)NN)
                 ? *reinterpret_cast<const unsigned int*>(fp + (size_t)s[k] * DF) : 0u;
        float x0, y0, x1, y1;
        fp8quad(v[0], x0, y0, x1, y1); a0 += x0; a1 += y0; a2 += x1; a3 += y1;
        fp8quad(v[1], x0, y0, x1, y1); c0 += x0; c1 += y0; c2 += x1; c3 += y1;
        fp8quad(v[2], x0, y0, x1, y1); a0 += x0; a1 += y0; a2 += x1; a3 += y1;
        fp8quad(v[3], x0, y0, x1, y1); c0 += x0; c1 += y0; c2 += x1; c3 += y1;
        fp8quad(v[4], x0, y0, x1, y1); a0 += x0; a1 += y0; a2 += x1; a3 += y1;
        fp8quad(v[5], x0, y0, x1, y1); c0 += x0; c1 += y0; c2 += x1; c3 += y1;
        fp8quad(v[6], x0, y0, x1, y1); a0 += x0; a1 += y0; a2 += x1; a3 += y1;
        fp8quad(v[7], x0, y0, x1, y1); c0 += x0; c1 += y0; c2 += x1; c3 += y1;
    }

    const float sc = 1.0f / fmaxf((float)(e - b), 1.0f);
    float s0 = (a0 + c0) * sc, s1 = (a1 + c1) * sc;
    float s2 = (a2 + c2) * sc, s3 = (a3 + c3) * sc;
    uint2 o;
    o.x = (unsigned)f2bf(s0) | ((unsigned)f2bf(s1) << 16);
    o.y = (unsigned)f2bf(s2) | ((unsigned)f2bf(s3) << 16);
    *reinterpret_cast<uint2*>(agg + (size_t)node * DF + lane32 * 4) = o;
}

// ---------------- MFMA GEMM (layer 1 + both layer-2 projections) -----------
// A-frag: lane holds A[row = lane&15][k = (lane>>4)*8 + j]
#define G_ROWS 64
#define LDSW 136

__global__ __launch_bounds__(256) void gemm1_kernel(const unsigned short* __restrict__ aggb,
                                                    const unsigned short* __restrict__ xb,
                                                    const unsigned short* __restrict__ w1p,
                                                    const unsigned short* __restrict__ w2lp,
                                                    const unsigned short* __restrict__ w2rp,
                                                    const float* __restrict__ b1,
                                                    const float* __restrict__ b2,
                                                    unsigned short* __restrict__ h2b,
                                                    unsigned short* __restrict__ h2rb) {
    __shared__ unsigned short sA[G_ROWS * LDSW];
    __shared__ unsigned short sX[G_ROWS * LDSW];
    const int t = threadIdx.x;
    const int row0 = blockIdx.x * G_ROWS;

    for (int i = t; i < G_ROWS * 16; i += 256) {
        int r = i >> 4, ch = i & 15;
        int sr = row0 + r; if (sr > NN - 1) sr = NN - 1;
        *reinterpret_cast<uint4*>(&sA[r * LDSW + ch * 8]) =
            *reinterpret_cast<const uint4*>(aggb + (size_t)sr * DF + ch * 8);
        *reinterpret_cast<uint4*>(&sX[r * LDSW + ch * 8]) =
            *reinterpret_cast<const uint4*>(xb + (size_t)sr * DF + ch * 8);
    }
    __syncthreads();

    const int lane = t & 63;
    const int w = t >> 6;
    const int lr = lane & 15;
    const int hi = lane >> 4;
    f32x4 acc[8];
#pragma unroll
    for (int i = 0; i < 8; ++i) acc[i] = (f32x4){0.f, 0.f, 0.f, 0.f};

    const int arow = (w * 16 + lr) * LDSW + hi * 8;
#pragma unroll
    for (int half = 0; half < 2; ++half) {
        const unsigned short* base = half ? sX : sA;
#pragma unroll
        for (int kq = 0; kq < 4; ++kq) {
            bf16x8 a = __builtin_bit_cast(bf16x8,
                *reinterpret_cast<const uint4*>(&base[arow + kq * 32]));
            const unsigned short* wp = w1p + (size_t)(((half * 4 + kq) * 8) * 64 + lane) * 8;
#pragma unroll
            for (int ct = 0; ct < 8; ++ct) {
                bf16x8 b = __builtin_bit_cast(bf16x8,
                    *reinterpret_cast<const uint4*>(wp + ct * 512));
                acc[ct] = __builtin_amdgcn_mfma_f32_16x16x32_bf16(a, b, acc[ct], 0, 0, 0);
            }
        }
    }

    // relu + bias -> bf16 registers
    unsigned short hreg[8][4];
#pragma unroll
    for (int ct = 0; ct < 8; ++ct) {
        float bias = b1[ct * 16 + lr];
#pragma unroll
        for (int v = 0; v < 4; ++v) {
            hreg[ct][v] = f2bf(fmaxf(acc[ct][v] + bias, 0.f));
        }
    }

    __syncthreads();   // stage-1 LDS reads done before overwrite
#pragma unroll
    for (int ct = 0; ct < 8; ++ct) {
#pragma unroll
        for (int v = 0; v < 4; ++v) {
            sA[(w * 16 + hi * 4 + v) * LDSW + ct * 16 + lr] = hreg[ct][v];
        }
    }
    __syncthreads();

    // stages 2+3: h @ W2l and h @ W2r + b2 (48 padded cols each)
    f32x4 acc2[3], acc3[3];
#pragma unroll
    for (int i = 0; i < 3; ++i) {
        acc2[i] = (f32x4){0.f, 0.f, 0.f, 0.f};
        acc3[i] = (f32x4){0.f, 0.f, 0.f, 0.f};
    }
#pragma unroll
    for (int kq = 0; kq < 4; ++kq) {
        bf16x8 a = __builtin_bit_cast(bf16x8,
            *reinterpret_cast<const uint4*>(&sA[arow + kq * 32]));
        const unsigned short* wpl = w2lp + (size_t)((kq * 3) * 64 + lane) * 8;
        const unsigned short* wpr = w2rp + (size_t)((kq * 3) * 64 + lane) * 8;
#pragma unroll
        for (int ct = 0; ct < 3; ++ct) {
            bf16x8 bl = __builtin_bit_cast(bf16x8,
                *reinterpret_cast<const uint4*>(wpl + ct * 512));
            bf16x8 br = __builtin_bit_cast(bf16x8,
                *reinterpret_cast<const uint4*>(wpr + ct * 512));
            acc2[ct] = __builtin_amdgcn_mfma_f32_16x16x32_bf16(a, bl, acc2[ct], 0, 0, 0);
            acc3[ct] = __builtin_amdgcn_mfma_f32_16x16x32_bf16(a, br, acc3[ct], 0, 0, 0);
        }
    }
#pragma unroll
    for (int ct = 0; ct < 3; ++ct) {
        int col = ct * 16 + lr;
        float bias2 = (col < DOUT) ? b2[col] : 0.f;
#pragma unroll
        for (int v = 0; v < 4; ++v) {
            int row = row0 + w * 16 + hi * 4 + v;
            if (row < NN) {
                h2b[(size_t)row * D2 + col]  = f2bf(acc2[ct][v]);
                h2rb[(size_t)row * D2 + col] = f2bf(acc3[ct][v] + bias2);
            }
        }
    }
}

// ---------------- fused gather48 + log_softmax, 2 nodes per wave -----------
// each 32-lane half handles one node; lanes 0..19 of the half hold col pair
// {2l, 2l+1}. xor-shuffle reduce (offsets 16..1) stays within the half.
__global__ __launch_bounds__(256) void gather_finish_kernel(const unsigned short* __restrict__ h2b,
                                                            const unsigned short* __restrict__ h2rb,
                                                            const int2* __restrict__ ofs2,
                                                            const int* __restrict__ srcs,
                                                            float* __restrict__ out) {
    const int gid   = blockIdx.x * 256 + threadIdx.x;
    const int node  = gid >> 5;                 // 2 nodes per wave
    const int lane32 = threadIdx.x & 31;
    if (node >= NN) return;
    const int2 be = ofs2[node];
    const int b = be.x;
    const int e = be.y;
    const bool act = lane32 < 20;
    const unsigned short* fp = h2b + lane32 * 2;

    float ax0 = 0.f, ay0 = 0.f, ax1 = 0.f, ay1 = 0.f;
    float ax2 = 0.f, ay2 = 0.f, ax3 = 0.f, ay3 = 0.f;

    for (int j = b; j < e; j += 8) {
        int s[8];
#pragma unroll
        for (int k = 0; k < 8; ++k)
            s[k] = (j + k < e) ? srcs[j + k] : -1;
        unsigned int v[8];
#pragma unroll
        for (int k = 0; k < 8; ++k)
            v[k] = (act && (unsigned)s[k] < (unsigned)NN)
                 ? *reinterpret_cast<const unsigned int*>(fp + (size_t)s[k] * D2) : 0u;
        ax0 += __uint_as_float(v[0] << 16);  ay0 += __uint_as_float(v[0] & 0xffff0000u);
        ax1 += __uint_as_float(v[1] << 16);  ay1 += __uint_as_float(v[1] & 0xffff0000u);
        ax2 += __uint_as_float(v[2] << 16);  ay2 += __uint_as_float(v[2] & 0xffff0000u);
        ax3 += __uint_as_float(v[3] << 16);  ay3 += __uint_as_float(v[3] & 0xffff0000u);
        ax0 += __uint_as_float(v[4] << 16);  ay0 += __uint_as_float(v[4] & 0xffff0000u);
        ax1 += __uint_as_float(v[5] << 16);  ay1 += __uint_as_float(v[5] & 0xffff0000u);
        ax2 += __uint_as_float(v[6] << 16);  ay2 += __uint_as_float(v[6] & 0xffff0000u);
        ax3 += __uint_as_float(v[7] << 16);  ay3 += __uint_as_float(v[7] & 0xffff0000u);
    }

    const float sc = 1.0f / fmaxf((float)(e - b), 1.0f);
    float a0 = ((ax0 + ax1) + (ax2 + ax3)) * sc;
    float a1 = ((ay0 + ay1) + (ay2 + ay3)) * sc;

    float lv0 = -INFINITY, lv1 = -INFINITY;
    if (act) {
        unsigned int sv = *reinterpret_cast<const unsigned int*>(h2rb + (size_t)node * D2 + lane32 * 2);
        lv0 = a0 + __uint_as_float(sv << 16);
        lv1 = a1 + __uint_as_float(sv & 0xffff0000u);
    }

    float mx = fmaxf(lv0, lv1);
#pragma unroll
    for (int off = 16; off > 0; off >>= 1) mx = fmaxf(mx, __shfl_xor(mx, off));
    float e0 = act ? __expf(lv0 - mx) : 0.f;
    float e1 = act ? __expf(lv1 - mx) : 0.f;
    float s = e0 + e1;
#pragma unroll
    for (int off = 16; off > 0; off >>= 1) s += __shfl_xor(s, off);
    float lz = mx + __logf(s);
    if (act) {
        float2 o = make_float2(lv0 - lz, lv1 - lz);
        *reinterpret_cast<float2*>(out + (size_t)node * DOUT + lane32 * 2) = o;
    }
}

extern "C" void kernel_launch(void* const* d_in, const int* in_sizes, int n_in,
                              void* d_out, int out_size, void* d_ws, size_t ws_size,
                              hipStream_t stream) {
    const float* x   = (const float*)d_in[0];
    const int*   ei  = (const int*)d_in[1];
    const int*   src = ei;
    const int*   dst = ei + NE;
    const float* W1l = (const float*)d_in[2];
    const float* W1r = (const float*)d_in[3];
    const float* b1  = (const float*)d_in[4];
    const float* W2l = (const float*)d_in[5];
    const float* W2r = (const float*)d_in[6];
    const float* b2  = (const float*)d_in[7];
    float* out = (float*)d_out;

    int* ip    = (int*)d_ws;
    int* deg   = ip;              // 100000
    int* loc   = ip + 100000;     // 100000
    int* rank  = ip + 200000;     // 640000
    int* srcs  = ip + 840000;     // 640008
    int* part  = ip + 1480008;    // 512
    int2* ofs2 = (int2*)(ip + 1480520);  // 100000 int2, 8B aligned
    unsigned short* up    = (unsigned short*)(ip + 1680520);  // 16B aligned
    unsigned short* xb    = up;                   // NN*DF = 12,800,000
    unsigned short* aggb  = up + 12800000;        // NN*DF
    unsigned short* h2b   = up + 25600000;        // NN*48 = 4,800,000
    unsigned short* h2rb  = up + 30400000;        // NN*48
    unsigned short* w1p   = up + 35200000;        // 32768
    unsigned short* w2lp  = up + 35232768;        // 6144
    unsigned short* w2rp  = up + 35238912;        // 6144
    unsigned char*  xq    = (unsigned char*)(up + 35245056);  // NN*DF bytes

    zero_deg_kernel<<<391, 256, 0, stream>>>(deg);
    mega_kernel<<<MK_GRID, 256, 0, stream>>>(x, xb, xq, W1l, W1r, w1p,
                                             W2l, W2r, w2lp, w2rp, dst, deg, rank);

    scan_block_kernel<<<391, 256, 0, stream>>>(deg, loc, part);
    add_off_kernel<<<391, 256, 0, stream>>>(loc, part, deg, ofs2);
    fill_kernel<<<(NE + 255) / 256, 256, 0, stream>>>(src, dst, ofs2, rank, srcs);

    gather_mean_fp8_kernel<<<12500, 256, 0, stream>>>(xq, ofs2, srcs, aggb);
    gemm1_kernel<<<1563, 256, 0, stream>>>(aggb, xb, w1p, w2lp, w2rp, b1, b2, h2b, h2rb);
    gather_finish_kernel<<<12500, 256, 0, stream>>>(h2b, h2rb, ofs2, srcs, out);
}

// Round 18
// 135.376 us; speedup vs baseline: 1.1739x; 1.0939x over previous
//
#include <hip/hip_runtime.h>
#include <math.h>

#define NN 100000   // nodes
#define NE 640000   // edges
#define DF 128      // in/hidden feat
#define DOUT 40     // out feat
#define D2 48       // padded W2 cols

#define PBITS 9
#define PSIZE 512            // 1 << PBITS
#define NPART 196            // ceil(NN / PSIZE)
#define KA_BLOCKS 250
#define KA_EPB 2560          // 250 * 2560 = 640000 exactly
#define KA_ITER (KA_EPB / 256)
#define STAGE_CAP 4096

typedef short bf16x8 __attribute__((ext_vector_type(8)));
typedef float f32x4 __attribute__((ext_vector_type(4)));
typedef float f32x2 __attribute__((ext_vector_type(2)));

#if defined(__has_builtin)
#if __has_builtin(__builtin_amdgcn_cvt_pk_f32_fp8) && __has_builtin(__builtin_amdgcn_cvt_pk_fp8_f32)
#define HW_FP8 1
#endif
#endif
#ifndef HW_FP8
#define HW_FP8 0
#endif

__device__ __forceinline__ unsigned short f2bf(float f) {
    unsigned int u = __float_as_uint(f);
    u += 0x7fffu + ((u >> 16) & 1u);   // RNE
    return (unsigned short)(u >> 16);
}

__device__ __forceinline__ unsigned int f2fp8_manual(float f) {
    unsigned u = __float_as_uint(f);
    unsigned s = (u >> 24) & 0x80u;
    unsigned au = u & 0x7fffffffu;
    if (au > 0x43e00000u) au = 0x43e00000u;   // clamp |x| to 448
    au += 0x7ffffu + ((au >> 20) & 1u);       // RNE to 3-bit mantissa
    if (au < 0x3c800000u) return s;           // flush < 2^-6 to 0
    unsigned e = (au >> 23) - 120u;
    return s | (e << 3) | ((au >> 20) & 7u);
}

__device__ __forceinline__ unsigned short f2fp8x2(float x, float y) {
#if HW_FP8
    int v = __builtin_amdgcn_cvt_pk_fp8_f32(x, y, 0, false);
    return (unsigned short)(v & 0xffff);
#else
    return (unsigned short)(f2fp8_manual(x) | (f2fp8_manual(y) << 8));
#endif
}

__device__ __forceinline__ void fp8pair(unsigned short p, float& x, float& y) {
#if HW_FP8
    f32x2 r = __builtin_amdgcn_cvt_pk_f32_fp8((int)(unsigned)p, false);
    x = r.x; y = r.y;
#else
    unsigned lo = p & 0xffu, hi = (p >> 8) & 0xffu;
    x = __uint_as_float(((lo & 0x80u) << 24) | ((lo & 0x7fu) << 20)) * 0x1.0p120f;
    y = __uint_as_float(((hi & 0x80u) << 24) | ((hi & 0x7fu) << 20)) * 0x1.0p120f;
#endif
}

// decode 4 packed fp8 from one uint (lo word -> x0,y0; hi word -> x1,y1)
__device__ __forceinline__ void fp8quad(unsigned int q, float& x0, float& y0,
                                        float& x1, float& y1) {
#if HW_FP8
    f32x2 lo = __builtin_amdgcn_cvt_pk_f32_fp8((int)q, false);
    f32x2 hi = __builtin_amdgcn_cvt_pk_f32_fp8((int)q, true);
    x0 = lo.x; y0 = lo.y; x1 = hi.x; y1 = hi.y;
#else
    fp8pair((unsigned short)(q & 0xffffu), x0, y0);
    fp8pair((unsigned short)(q >> 16), x1, y1);
#endif
}

// ---------------- K0: zero partition histogram ----------------
__global__ __launch_bounds__(256) void zero_phist_kernel(int* __restrict__ phist) {
    phist[threadIdx.x] = 0;
}

// ---------------- mega: convert-x (bf16+fp8) || pack W1/W2 ----------------
#define MK_CONV 6250
#define MK_W1   (MK_CONV + 16)
#define MK_W2   (MK_W1 + 6)
#define MK_GRID MK_W2

__global__ __launch_bounds__(256) void mega_kernel(const float* __restrict__ x,
                                                   unsigned short* __restrict__ xb,
                                                   unsigned char* __restrict__ xq,
                                                   const float* __restrict__ W1l,
                                                   const float* __restrict__ W1r,
                                                   unsigned short* __restrict__ w1p,
                                                   const float* __restrict__ W2l,
                                                   const float* __restrict__ W2r,
                                                   unsigned short* __restrict__ w2lp,
                                                   unsigned short* __restrict__ w2rp) {
    const int bid = blockIdx.x;
    const int tid = threadIdx.x;
    if (bid < MK_CONV) {
        int i = (bid * 256 + tid) * 8;
        float4 a = *reinterpret_cast<const float4*>(x + i);
        float4 b = *reinterpret_cast<const float4*>(x + i + 4);
        uint4 o;
        o.x = (unsigned)f2bf(a.x) | ((unsigned)f2bf(a.y) << 16);
        o.y = (unsigned)f2bf(a.z) | ((unsigned)f2bf(a.w) << 16);
        o.z = (unsigned)f2bf(b.x) | ((unsigned)f2bf(b.y) << 16);
        o.w = (unsigned)f2bf(b.z) | ((unsigned)f2bf(b.w) << 16);
        *reinterpret_cast<uint4*>(xb + (size_t)i) = o;
        unsigned short q0 = f2fp8x2(a.x, a.y);
        unsigned short q1 = f2fp8x2(a.z, a.w);
        unsigned short q2 = f2fp8x2(b.x, b.y);
        unsigned short q3 = f2fp8x2(b.z, b.w);
        uint2 qo;
        qo.x = (unsigned)q0 | ((unsigned)q1 << 16);
        qo.y = (unsigned)q2 | ((unsigned)q3 << 16);
        *reinterpret_cast<uint2*>(xq + (size_t)i) = qo;
    } else if (bid < MK_W1) {
        // B-frag: lane holds B[k=(lane>>4)*8+j][col=ct*16+(lane&15)]
        int t = (bid - MK_CONV) * 256 + tid;     // 4096 = 8kt * 8ct * 64
        int lane = t & 63;
        int ct = (t >> 6) & 7;
        int kt = t >> 9;
        int c  = ct * 16 + (lane & 15);
        int k0 = (kt & 3) * 32 + (lane >> 4) * 8;
        const float* W = (kt < 4) ? W1l : W1r;
        unsigned int o[4];
#pragma unroll
        for (int j = 0; j < 4; ++j) {
            unsigned int lo = f2bf(W[(size_t)(k0 + 2 * j) * DF + c]);
            unsigned int hi = f2bf(W[(size_t)(k0 + 2 * j + 1) * DF + c]);
            o[j] = lo | (hi << 16);
        }
        uint4 v; v.x = o[0]; v.y = o[1]; v.z = o[2]; v.w = o[3];
        *reinterpret_cast<uint4*>(w1p + (size_t)t * 8) = v;
    } else {
        int t = (bid - MK_W1) * 256 + tid;       // 1536 = 2 * 4kt * 3ct * 64
        if (t < 1536) {
            int lane = t & 63;
            int g  = t >> 6;       // 0..23
            int ct = g % 3;
            int kt = g / 3;        // <4 -> W2l else W2r
            int c  = ct * 16 + (lane & 15);
            int k0 = (kt & 3) * 32 + (lane >> 4) * 8;
            const float* W = (kt < 4) ? W2l : W2r;
            unsigned short* dstp = (kt < 4) ? w2lp : w2rp;
            int slot = ((kt & 3) * 3 + ct) * 64 + lane;
            unsigned int o[4];
#pragma unroll
            for (int j = 0; j < 4; ++j) {
                unsigned int lo = (c < DOUT) ? f2bf(W[(size_t)(k0 + 2 * j) * DOUT + c]) : 0u;
                unsigned int hi = (c < DOUT) ? f2bf(W[(size_t)(k0 + 2 * j + 1) * DOUT + c]) : 0u;
                o[j] = lo | (hi << 16);
            }
            uint4 v; v.x = o[0]; v.y = o[1]; v.z = o[2]; v.w = o[3];
            *reinterpret_cast<uint4*>(dstp + (size_t)slot * 8) = v;
        }
    }
}

// ---------------- K_a: partition histogram (LDS-privatized) ----------------
__global__ __launch_bounds__(256) void part_hist_kernel(const int* __restrict__ dst,
                                                        int* __restrict__ phist) {
    __shared__ int h[256];
    const int t = threadIdx.x;
    h[t] = 0;
    __syncthreads();
    const int base = blockIdx.x * KA_EPB;
#pragma unroll
    for (int k = 0; k < KA_ITER; ++k) {
        int p = dst[base + k * 256 + t] >> PBITS;
        atomicAdd(&h[p], 1);
    }
    __syncthreads();
    if (h[t]) atomicAdd(&phist[t], h[t]);
}

// ---------------- K_b: scan partition sizes -> pbase, init gcur ------------
__global__ __launch_bounds__(256) void part_scan_kernel(const int* __restrict__ phist,
                                                        int* __restrict__ pbase,
                                                        int* __restrict__ gcur) {
    __shared__ int tmp[256];
    const int t = threadIdx.x;
    int v = (t < NPART) ? phist[t] : 0;
    tmp[t] = v;
    __syncthreads();
    for (int off = 1; off < 256; off <<= 1) {
        int a = (t >= off) ? tmp[t - off] : 0;
        __syncthreads();
        tmp[t] += a;
        __syncthreads();
    }
    int excl = tmp[t] - v;
    if (t < NPART) { pbase[t] = excl; gcur[t] = excl; }
    if (t == NPART) pbase[t] = NE;
}

// ---------------- K_c: partition scatter (block-local counting sort) -------
// Block LDS-sorts its 2560 edges by partition, reserves disjoint global
// ranges (196 atomics/block), writes sorted runs coalesced.
__global__ __launch_bounds__(256) void part_scatter_kernel(const int* __restrict__ src,
                                                           const int* __restrict__ dst,
                                                           int* __restrict__ gcur,
                                                           uint2* __restrict__ epart) {
    __shared__ int h[256];
    __shared__ int lbase[256];
    __shared__ int gbase[256];
    __shared__ int cur[256];
    __shared__ uint2 ed[KA_EPB];   // 20 KB
    const int t = threadIdx.x;
    h[t] = 0;
    __syncthreads();
    const int base = blockIdx.x * KA_EPB;
    int   ps[KA_ITER];
    uint2 es[KA_ITER];
#pragma unroll
    for (int k = 0; k < KA_ITER; ++k) {
        int e = base + k * 256 + t;
        int s = src[e], d = dst[e];
        es[k] = make_uint2((unsigned)s, (unsigned)d);
        ps[k] = d >> PBITS;
        atomicAdd(&h[ps[k]], 1);
    }
    __syncthreads();
    int v = h[t];
    lbase[t] = v;
    __syncthreads();
    for (int off = 1; off < 256; off <<= 1) {
        int a = (t >= off) ? lbase[t - off] : 0;
        __syncthreads();
        lbase[t] += a;
        __syncthreads();
    }
    int excl = lbase[t] - v;
    lbase[t] = excl;            // own slot only
    cur[t]   = excl;
    if (t < NPART && v > 0) gbase[t] = atomicAdd(&gcur[t], v);
    __syncthreads();
    // scatter into LDS sorted by partition
#pragma unroll
    for (int k = 0; k < KA_ITER; ++k) {
        int pos = atomicAdd(&cur[ps[k]], 1);
        ed[pos] = es[k];
    }
    __syncthreads();
    // coalesced write-out (runs per partition)
    for (int i = t; i < KA_EPB; i += 256) {
        uint2 e2 = ed[i];
        int p = (int)(e2.y >> PBITS);
        epart[gbase[p] + (i - lbase[p])] = e2;
    }
}

// ---------------- K_d: per-partition local CSR -----------------------------
// One block per partition: LDS count + scan over 512 nodes, LDS-staged src
// scatter, coalesced srcs write, ofs2 write.
__global__ __launch_bounds__(256) void local_csr_kernel(const uint2* __restrict__ epart,
                                                        const int* __restrict__ pbase,
                                                        int2* __restrict__ ofs2,
                                                        int* __restrict__ srcs) {
    __shared__ int cnt[PSIZE];
    __shared__ int cur[PSIZE];
    __shared__ int scantmp[256];
    __shared__ int stage[STAGE_CAP];   // 16 KB
    const int p = blockIdx.x;
    const int t = threadIdx.x;
    const int eb = pbase[p], ee = pbase[p + 1];
    const int ecount = ee - eb;
    cnt[t] = 0; cnt[t + 256] = 0;
    __syncthreads();
    for (int i = t; i < ecount; i += 256) {
        int nid = (int)epart[eb + i].y - (p << PBITS);
        atomicAdd(&cnt[nid], 1);
    }
    __syncthreads();
    // scan 512 (thread owns 2 consecutive)
    int c0 = cnt[2 * t], c1 = cnt[2 * t + 1];
    int pair = c0 + c1;
    scantmp[t] = pair;
    __syncthreads();
    for (int off = 1; off < 256; off <<= 1) {
        int a = (t >= off) ? scantmp[t - off] : 0;
        __syncthreads();
        scantmp[t] += a;
        __syncthreads();
    }
    int pexcl = scantmp[t] - pair;
    cur[2 * t]     = pexcl;
    cur[2 * t + 1] = pexcl + c0;
    // ofs2 (uses registers only)
    int n0 = (p << PBITS) + 2 * t;
    if (n0 < NN)     ofs2[n0]     = make_int2(eb + pexcl,      eb + pexcl + c0);
    if (n0 + 1 < NN) ofs2[n0 + 1] = make_int2(eb + pexcl + c0, eb + pexcl + c0 + c1);
    __syncthreads();
    // pass 2: scatter srcs via LDS stage
    for (int i = t; i < ecount; i += 256) {
        uint2 e2 = epart[eb + i];
        int nid = (int)e2.y - (p << PBITS);
        int slot = atomicAdd(&cur[nid], 1);
        if (slot < STAGE_CAP) stage[slot] = (int)e2.x;
        else srcs[eb + slot] = (int)e2.x;   // overflow fallback (won't trigger)
    }
    __syncthreads();
    int lim = (ecount < STAGE_CAP) ? ecount : STAGE_CAP;
    for (int i = t; i < lim; i += 256) srcs[eb + i] = stage[i];
}

// ---------------- gather-mean, 128-dim fp8 in -> bf16 out ------------------
// 2 nodes per wave: each 32-lane half owns one node; lane holds 4 fp8 dims.
__global__ __launch_bounds__(256) void gather_mean_fp8_kernel(const unsigned char* __restrict__ xq,
                                                              const int2* __restrict__ ofs2,
                                                              const int* __restrict__ srcs,
                                                              unsigned short* __restrict__ agg) {
    const int gid    = blockIdx.x * 256 + threadIdx.x;
    const int node   = gid >> 5;               // 2 nodes per wave
    const int lane32 = threadIdx.x & 31;
    if (node >= NN) return;
    const int2 be = ofs2[node];
    const int b = be.x;
    const int e = be.y;
    const unsigned char* fp = xq + lane32 * 4;

    float a0 = 0.f, a1 = 0.f, a2 = 0.f, a3 = 0.f;
    float c0 = 0.f, c1 = 0.f, c2 = 0.f, c3 = 0.f;

    for (int j = b; j < e; j += 8) {
        int s[8];
#pragma unroll
        for (int k = 0; k < 8; ++k)
            s[k] = (j + k < e) ? srcs[j + k] : -1;
        unsigned int v[8];
#pragma unroll
        for (int k = 0; k < 8; ++k)
            v[k] = ((unsigned)s[k] < (unsigned)NN)
                 ? *reinterpret_cast<const unsigned int*>(fp + (size_t)s[k] * DF) : 0u;
        float x0, y0, x1, y1;
        fp8quad(v[0], x0, y0, x1, y1); a0 += x0; a1 += y0; a2 += x1; a3 += y1;
        fp8quad(v[1], x0, y0, x1, y1); c0 += x0; c1 += y0; c2 += x1; c3 += y1;
        fp8quad(v[2], x0, y0, x1, y1); a0 += x0; a1 += y0; a2 += x1; a3 += y1;
        fp8quad(v[3], x0, y0, x1, y1); c0 += x0; c1 += y0; c2 += x1; c3 += y1;
        fp8quad(v[4], x0, y0, x1, y1); a0 += x0; a1 += y0; a2 += x1; a3 += y1;
        fp8quad(v[5], x0, y0, x1, y1); c0 += x0; c1 += y0; c2 += x1; c3 += y1;
        fp8quad(v[6], x0, y0, x1, y1); a0 += x0; a1 += y0; a2 += x1; a3 += y1;
        fp8quad(v[7], x0, y0, x1, y1); c0 += x0; c1 += y0; c2 += x1; c3 += y1;
    }

    const float sc = 1.0f / fmaxf((float)(e - b), 1.0f);
    float s0 = (a0 + c0) * sc, s1 = (a1 + c1) * sc;
    float s2 = (a2 + c2) * sc, s3 = (a3 + c3) * sc;
    uint2 o;
    o.x = (unsigned)f2bf(s0) | ((unsigned)f2bf(s1) << 16);
    o.y = (unsigned)f2bf(s2) | ((unsigned)f2bf(s3) << 16);
    *reinterpret_cast<uint2*>(agg + (size_t)node * DF + lane32 * 4) = o;
}

// ---------------- MFMA GEMM (layer 1 + both layer-2 projections) -----------
// A-frag: lane holds A[row = lane&15][k = (lane>>4)*8 + j]
#define G_ROWS 64
#define LDSW 136

__global__ __launch_bounds__(256) void gemm1_kernel(const unsigned short* __restrict__ aggb,
                                                    const unsigned short* __restrict__ xb,
                                                    const unsigned short* __restrict__ w1p,
                                                    const unsigned short* __restrict__ w2lp,
                                                    const unsigned short* __restrict__ w2rp,
                                                    const float* __restrict__ b1,
                                                    const float* __restrict__ b2,
                                                    unsigned short* __restrict__ h2b,
                                                    unsigned short* __restrict__ h2rb) {
    __shared__ unsigned short sA[G_ROWS * LDSW];
    __shared__ unsigned short sX[G_ROWS * LDSW];
    const int t = threadIdx.x;
    const int row0 = blockIdx.x * G_ROWS;

    for (int i = t; i < G_ROWS * 16; i += 256) {
        int r = i >> 4, ch = i & 15;
        int sr = row0 + r; if (sr > NN - 1) sr = NN - 1;
        *reinterpret_cast<uint4*>(&sA[r * LDSW + ch * 8]) =
            *reinterpret_cast<const uint4*>(aggb + (size_t)sr * DF + ch * 8);
        *reinterpret_cast<uint4*>(&sX[r * LDSW + ch * 8]) =
            *reinterpret_cast<const uint4*>(xb + (size_t)sr * DF + ch * 8);
    }
    __syncthreads();

    const int lane = t & 63;
    const int w = t >> 6;
    const int lr = lane & 15;
    const int hi = lane >> 4;
    f32x4 acc[8];
#pragma unroll
    for (int i = 0; i < 8; ++i) acc[i] = (f32x4){0.f, 0.f, 0.f, 0.f};

    const int arow = (w * 16 + lr) * LDSW + hi * 8;
#pragma unroll
    for (int half = 0; half < 2; ++half) {
        const unsigned short* base = half ? sX : sA;
#pragma unroll
        for (int kq = 0; kq < 4; ++kq) {
            bf16x8 a = __builtin_bit_cast(bf16x8,
                *reinterpret_cast<const uint4*>(&base[arow + kq * 32]));
            const unsigned short* wp = w1p + (size_t)(((half * 4 + kq) * 8) * 64 + lane) * 8;
#pragma unroll
            for (int ct = 0; ct < 8; ++ct) {
                bf16x8 b = __builtin_bit_cast(bf16x8,
                    *reinterpret_cast<const uint4*>(wp + ct * 512));
                acc[ct] = __builtin_amdgcn_mfma_f32_16x16x32_bf16(a, b, acc[ct], 0, 0, 0);
            }
        }
    }

    // relu + bias -> bf16 registers
    unsigned short hreg[8][4];
#pragma unroll
    for (int ct = 0; ct < 8; ++ct) {
        float bias = b1[ct * 16 + lr];
#pragma unroll
        for (int v = 0; v < 4; ++v) {
            hreg[ct][v] = f2bf(fmaxf(acc[ct][v] + bias, 0.f));
        }
    }

    __syncthreads();   // stage-1 LDS reads done before overwrite
#pragma unroll
    for (int ct = 0; ct < 8; ++ct) {
#pragma unroll
        for (int v = 0; v < 4; ++v) {
            sA[(w * 16 + hi * 4 + v) * LDSW + ct * 16 + lr] = hreg[ct][v];
        }
    }
    __syncthreads();

    // stages 2+3: h @ W2l and h @ W2r + b2 (48 padded cols each)
    f32x4 acc2[3], acc3[3];
#pragma unroll
    for (int i = 0; i < 3; ++i) {
        acc2[i] = (f32x4){0.f, 0.f, 0.f, 0.f};
        acc3[i] = (f32x4){0.f, 0.f, 0.f, 0.f};
    }
#pragma unroll
    for (int kq = 0; kq < 4; ++kq) {
        bf16x8 a = __builtin_bit_cast(bf16x8,
            *reinterpret_cast<const uint4*>(&sA[arow + kq * 32]));
        const unsigned short* wpl = w2lp + (size_t)((kq * 3) * 64 + lane) * 8;
        const unsigned short* wpr = w2rp + (size_t)((kq * 3) * 64 + lane) * 8;
#pragma unroll
        for (int ct = 0; ct < 3; ++ct) {
            bf16x8 bl = __builtin_bit_cast(bf16x8,
                *reinterpret_cast<const uint4*>(wpl + ct * 512));
            bf16x8 br = __builtin_bit_cast(bf16x8,
                *reinterpret_cast<const uint4*>(wpr + ct * 512));
            acc2[ct] = __builtin_amdgcn_mfma_f32_16x16x32_bf16(a, bl, acc2[ct], 0, 0, 0);
            acc3[ct] = __builtin_amdgcn_mfma_f32_16x16x32_bf16(a, br, acc3[ct], 0, 0, 0);
        }
    }
#pragma unroll
    for (int ct = 0; ct < 3; ++ct) {
        int col = ct * 16 + lr;
        float bias2 = (col < DOUT) ? b2[col] : 0.f;
#pragma unroll
        for (int v = 0; v < 4; ++v) {
            int row = row0 + w * 16 + hi * 4 + v;
            if (row < NN) {
                h2b[(size_t)row * D2 + col]  = f2bf(acc2[ct][v]);
                h2rb[(size_t)row * D2 + col] = f2bf(acc3[ct][v] + bias2);
            }
        }
    }
}

// ---------------- fused gather48 + log_softmax, 2 nodes per wave -----------
__global__ __launch_bounds__(256) void gather_finish_kernel(const unsigned short* __restrict__ h2b,
                                                            const unsigned short* __restrict__ h2rb,
                                                            const int2* __restrict__ ofs2,
                                                            const int* __restrict__ srcs,
                                                            float* __restrict__ out) {
    const int gid   = blockIdx.x * 256 + threadIdx.x;
    const int node  = gid >> 5;                 // 2 nodes per wave
    const int lane32 = threadIdx.x & 31;
    if (node >= NN) return;
    const int2 be = ofs2[node];
    const int b = be.x;
    const int e = be.y;
    const bool act = lane32 < 20;
    const unsigned short* fp = h2b + lane32 * 2;

    float ax0 = 0.f, ay0 = 0.f, ax1 = 0.f, ay1 = 0.f;
    float ax2 = 0.f, ay2 = 0.f, ax3 = 0.f, ay3 = 0.f;

    for (int j = b; j < e; j += 8) {
        int s[8];
#pragma unroll
        for (int k = 0; k < 8; ++k)
            s[k] = (j + k < e) ? srcs[j + k] : -1;
        unsigned int v[8];
#pragma unroll
        for (int k = 0; k < 8; ++k)
            v[k] = (act && (unsigned)s[k] < (unsigned)NN)
                 ? *reinterpret_cast<const unsigned int*>(fp + (size_t)s[k] * D2) : 0u;
        ax0 += __uint_as_float(v[0] << 16);  ay0 += __uint_as_float(v[0] & 0xffff0000u);
        ax1 += __uint_as_float(v[1] << 16);  ay1 += __uint_as_float(v[1] & 0xffff0000u);
        ax2 += __uint_as_float(v[2] << 16);  ay2 += __uint_as_float(v[2] & 0xffff0000u);
        ax3 += __uint_as_float(v[3] << 16);  ay3 += __uint_as_float(v[3] & 0xffff0000u);
        ax0 += __uint_as_float(v[4] << 16);  ay0 += __uint_as_float(v[4] & 0xffff0000u);
        ax1 += __uint_as_float(v[5] << 16);  ay1 += __uint_as_float(v[5] & 0xffff0000u);
        ax2 += __uint_as_float(v[6] << 16);  ay2 += __uint_as_float(v[6] & 0xffff0000u);
        ax3 += __uint_as_float(v[7] << 16);  ay3 += __uint_as_float(v[7] & 0xffff0000u);
    }

    const float sc = 1.0f / fmaxf((float)(e - b), 1.0f);
    float a0 = ((ax0 + ax1) + (ax2 + ax3)) * sc;
    float a1 = ((ay0 + ay1) + (ay2 + ay3)) * sc;

    float lv0 = -INFINITY, lv1 = -INFINITY;
    if (act) {
        unsigned int sv = *reinterpret_cast<const unsigned int*>(h2rb + (size_t)node * D2 + lane32 * 2);
        lv0 = a0 + __uint_as_float(sv << 16);
        lv1 = a1 + __uint_as_float(sv & 0xffff0000u);
    }

    float mx = fmaxf(lv0, lv1);
#pragma unroll
    for (int off = 16; off > 0; off >>= 1) mx = fmaxf(mx, __shfl_xor(mx, off));
    float e0 = act ? __expf(lv0 - mx) : 0.f;
    float e1 = act ? __expf(lv1 - mx) : 0.f;
    float s = e0 + e1;
#pragma unroll
    for (int off = 16; off > 0; off >>= 1) s += __shfl_xor(s, off);
    float lz = mx + __logf(s);
    if (act) {
        float2 o = make_float2(lv0 - lz, lv1 - lz);
        *reinterpret_cast<float2*>(out + (size_t)node * DOUT + lane32 * 2) = o;
    }
}

extern "C" void kernel_launch(void* const* d_in, const int* in_sizes, int n_in,
                              void* d_out, int out_size, void* d_ws, size_t ws_size,
                              hipStream_t stream) {
    const float* x   = (const float*)d_in[0];
    const int*   ei  = (const int*)d_in[1];
    const int*   src = ei;
    const int*   dst = ei + NE;
    const float* W1l = (const float*)d_in[2];
    const float* W1r = (const float*)d_in[3];
    const float* b1  = (const float*)d_in[4];
    const float* W2l = (const float*)d_in[5];
    const float* W2r = (const float*)d_in[6];
    const float* b2  = (const float*)d_in[7];
    float* out = (float*)d_out;

    int* ip     = (int*)d_ws;
    int* phist  = ip;                 // 256
    int* pbase  = ip + 256;           // 256 (need 197)
    int* gcur   = ip + 512;           // 256
    int* srcs   = ip + 768;           // 640008
    uint2* epart = (uint2*)(ip + 640776);       // NE uint2 = 1,280,000 ints
    int2*  ofs2  = (int2*)(ip + 1920776);       // NN int2  =   200,000 ints
    unsigned short* up    = (unsigned short*)(ip + 2120776);  // 8B aligned
    unsigned short* xb    = up;                   // NN*DF = 12,800,000
    unsigned short* aggb  = up + 12800000;        // NN*DF
    unsigned short* h2b   = up + 25600000;        // NN*48 = 4,800,000
    unsigned short* h2rb  = up + 30400000;        // NN*48
    unsigned short* w1p   = up + 35200000;        // 32768
    unsigned short* w2lp  = up + 35232768;        // 6144
    unsigned short* w2rp  = up + 35238912;        // 6144
    unsigned char*  xq    = (unsigned char*)(up + 35245056);  // NN*DF bytes

    mega_kernel<<<MK_GRID, 256, 0, stream>>>(x, xb, xq, W1l, W1r, w1p,
                                             W2l, W2r, w2lp, w2rp);

    zero_phist_kernel<<<1, 256, 0, stream>>>(phist);
    part_hist_kernel<<<KA_BLOCKS, 256, 0, stream>>>(dst, phist);
    part_scan_kernel<<<1, 256, 0, stream>>>(phist, pbase, gcur);
    part_scatter_kernel<<<KA_BLOCKS, 256, 0, stream>>>(src, dst, gcur, epart);
    local_csr_kernel<<<NPART, 256, 0, stream>>>(epart, pbase, ofs2, srcs);

    gather_mean_fp8_kernel<<<12500, 256, 0, stream>>>(xq, ofs2, srcs, aggb);
    gemm1_kernel<<<1563, 256, 0, stream>>>(aggb, xb, w1p, w2lp, w2rp, b1, b2, h2b, h2rb);
    gather_finish_kernel<<<12500, 256, 0, stream>>>(h2b, h2rb, ofs2, srcs, out);
}

// Round 19
// 133.086 us; speedup vs baseline: 1.1941x; 1.0172x over previous
//
#include <hip/hip_runtime.h>
#include <math.h>

#define NN 100000   // nodes
#define NE 640000   // edges
#define DF 128      // in/hidden feat
#define DOUT 40     // out feat
#define D2 48       // padded W2 cols

#define PBITS 9
#define PSIZE 512            // 1 << PBITS
#define NPART 196            // ceil(NN / PSIZE)
#define KA_BLOCKS 250
#define KA_EPB 2560          // 250 * 2560 = 640000 exactly
#define KA_ITER (KA_EPB / 256)
#define STAGE_CAP 4096

typedef short bf16x8 __attribute__((ext_vector_type(8)));
typedef float f32x4 __attribute__((ext_vector_type(4)));
typedef float f32x2 __attribute__((ext_vector_type(2)));

#if defined(__has_builtin)
#if __has_builtin(__builtin_amdgcn_cvt_pk_f32_fp8) && __has_builtin(__builtin_amdgcn_cvt_pk_fp8_f32)
#define HW_FP8 1
#endif
#endif
#ifndef HW_FP8
#define HW_FP8 0
#endif

__device__ __forceinline__ unsigned short f2bf(float f) {
    unsigned int u = __float_as_uint(f);
    u += 0x7fffu + ((u >> 16) & 1u);   // RNE
    return (unsigned short)(u >> 16);
}

__device__ __forceinline__ unsigned int f2fp8_manual(float f) {
    unsigned u = __float_as_uint(f);
    unsigned s = (u >> 24) & 0x80u;
    unsigned au = u & 0x7fffffffu;
    if (au > 0x43e00000u) au = 0x43e00000u;   // clamp |x| to 448
    au += 0x7ffffu + ((au >> 20) & 1u);       // RNE to 3-bit mantissa
    if (au < 0x3c800000u) return s;           // flush < 2^-6 to 0
    unsigned e = (au >> 23) - 120u;
    return s | (e << 3) | ((au >> 20) & 7u);
}

__device__ __forceinline__ unsigned short f2fp8x2(float x, float y) {
#if HW_FP8
    int v = __builtin_amdgcn_cvt_pk_fp8_f32(x, y, 0, false);
    return (unsigned short)(v & 0xffff);
#else
    return (unsigned short)(f2fp8_manual(x) | (f2fp8_manual(y) << 8));
#endif
}

__device__ __forceinline__ void fp8pair(unsigned short p, float& x, float& y) {
#if HW_FP8
    f32x2 r = __builtin_amdgcn_cvt_pk_f32_fp8((int)(unsigned)p, false);
    x = r.x; y = r.y;
#else
    unsigned lo = p & 0xffu, hi = (p >> 8) & 0xffu;
    x = __uint_as_float(((lo & 0x80u) << 24) | ((lo & 0x7fu) << 20)) * 0x1.0p120f;
    y = __uint_as_float(((hi & 0x80u) << 24) | ((hi & 0x7fu) << 20)) * 0x1.0p120f;
#endif
}

// decode 4 packed fp8 from one uint (lo word -> x0,y0; hi word -> x1,y1)
__device__ __forceinline__ void fp8quad(unsigned int q, float& x0, float& y0,
                                        float& x1, float& y1) {
#if HW_FP8
    f32x2 lo = __builtin_amdgcn_cvt_pk_f32_fp8((int)q, false);
    f32x2 hi = __builtin_amdgcn_cvt_pk_f32_fp8((int)q, true);
    x0 = lo.x; y0 = lo.y; x1 = hi.x; y1 = hi.y;
#else
    fp8pair((unsigned short)(q & 0xffffu), x0, y0);
    fp8pair((unsigned short)(q >> 16), x1, y1);
#endif
}

// ---------------- mega: convert-x || pack W1/W2 || zero phist+gcur ---------
#define MK_CONV 6250
#define MK_W1   (MK_CONV + 16)
#define MK_W2   (MK_W1 + 6)
#define MK_GRID (MK_W2 + 1)      // +1 block zeroes phist & gcur

__global__ __launch_bounds__(256) void mega_kernel(const float* __restrict__ x,
                                                   unsigned short* __restrict__ xb,
                                                   unsigned char* __restrict__ xq,
                                                   const float* __restrict__ W1l,
                                                   const float* __restrict__ W1r,
                                                   unsigned short* __restrict__ w1p,
                                                   const float* __restrict__ W2l,
                                                   const float* __restrict__ W2r,
                                                   unsigned short* __restrict__ w2lp,
                                                   unsigned short* __restrict__ w2rp,
                                                   int* __restrict__ phist,
                                                   int* __restrict__ gcur) {
    const int bid = blockIdx.x;
    const int tid = threadIdx.x;
    if (bid < MK_CONV) {
        int i = (bid * 256 + tid) * 8;
        float4 a = *reinterpret_cast<const float4*>(x + i);
        float4 b = *reinterpret_cast<const float4*>(x + i + 4);
        uint4 o;
        o.x = (unsigned)f2bf(a.x) | ((unsigned)f2bf(a.y) << 16);
        o.y = (unsigned)f2bf(a.z) | ((unsigned)f2bf(a.w) << 16);
        o.z = (unsigned)f2bf(b.x) | ((unsigned)f2bf(b.y) << 16);
        o.w = (unsigned)f2bf(b.z) | ((unsigned)f2bf(b.w) << 16);
        *reinterpret_cast<uint4*>(xb + (size_t)i) = o;
        unsigned short q0 = f2fp8x2(a.x, a.y);
        unsigned short q1 = f2fp8x2(a.z, a.w);
        unsigned short q2 = f2fp8x2(b.x, b.y);
        unsigned short q3 = f2fp8x2(b.z, b.w);
        uint2 qo;
        qo.x = (unsigned)q0 | ((unsigned)q1 << 16);
        qo.y = (unsigned)q2 | ((unsigned)q3 << 16);
        *reinterpret_cast<uint2*>(xq + (size_t)i) = qo;
    } else if (bid < MK_W1) {
        // B-frag: lane holds B[k=(lane>>4)*8+j][col=ct*16+(lane&15)]
        int t = (bid - MK_CONV) * 256 + tid;     // 4096 = 8kt * 8ct * 64
        int lane = t & 63;
        int ct = (t >> 6) & 7;
        int kt = t >> 9;
        int c  = ct * 16 + (lane & 15);
        int k0 = (kt & 3) * 32 + (lane >> 4) * 8;
        const float* W = (kt < 4) ? W1l : W1r;
        unsigned int o[4];
#pragma unroll
        for (int j = 0; j < 4; ++j) {
            unsigned int lo = f2bf(W[(size_t)(k0 + 2 * j) * DF + c]);
            unsigned int hi = f2bf(W[(size_t)(k0 + 2 * j + 1) * DF + c]);
            o[j] = lo | (hi << 16);
        }
        uint4 v; v.x = o[0]; v.y = o[1]; v.z = o[2]; v.w = o[3];
        *reinterpret_cast<uint4*>(w1p + (size_t)t * 8) = v;
    } else if (bid < MK_W2) {
        int t = (bid - MK_W1) * 256 + tid;       // 1536 = 2 * 4kt * 3ct * 64
        if (t < 1536) {
            int lane = t & 63;
            int g  = t >> 6;       // 0..23
            int ct = g % 3;
            int kt = g / 3;        // <4 -> W2l else W2r
            int c  = ct * 16 + (lane & 15);
            int k0 = (kt & 3) * 32 + (lane >> 4) * 8;
            const float* W = (kt < 4) ? W2l : W2r;
            unsigned short* dstp = (kt < 4) ? w2lp : w2rp;
            int slot = ((kt & 3) * 3 + ct) * 64 + lane;
            unsigned int o[4];
#pragma unroll
            for (int j = 0; j < 4; ++j) {
                unsigned int lo = (c < DOUT) ? f2bf(W[(size_t)(k0 + 2 * j) * DOUT + c]) : 0u;
                unsigned int hi = (c < DOUT) ? f2bf(W[(size_t)(k0 + 2 * j + 1) * DOUT + c]) : 0u;
                o[j] = lo | (hi << 16);
            }
            uint4 v; v.x = o[0]; v.y = o[1]; v.z = o[2]; v.w = o[3];
            *reinterpret_cast<uint4*>(dstp + (size_t)slot * 8) = v;
        }
    } else {
        phist[tid] = 0;
        gcur[tid]  = 0;
    }
}

// ---------------- K_a: partition histogram (LDS-privatized) ----------------
__global__ __launch_bounds__(256) void part_hist_kernel(const int* __restrict__ dst,
                                                        int* __restrict__ phist) {
    __shared__ int h[256];
    const int t = threadIdx.x;
    h[t] = 0;
    __syncthreads();
    const int base = blockIdx.x * KA_EPB;
#pragma unroll
    for (int k = 0; k < KA_ITER; ++k) {
        int p = dst[base + k * 256 + t] >> PBITS;
        atomicAdd(&h[p], 1);
    }
    __syncthreads();
    if (h[t]) atomicAdd(&phist[t], h[t]);
}

// ---------------- K_c: partition scatter (block-local counting sort) -------
// Each block recomputes the partition-scan locally (196 ints), LDS-sorts its
// 2560 edges by partition, reserves disjoint global ranges, writes coalesced.
__global__ __launch_bounds__(256) void part_scatter_kernel(const int* __restrict__ src,
                                                           const int* __restrict__ dst,
                                                           const int* __restrict__ phist,
                                                           int* __restrict__ gcur,
                                                           uint2* __restrict__ epart) {
    __shared__ int h[256];
    __shared__ int pb[256];
    __shared__ int lbase[256];
    __shared__ int gbase[256];
    __shared__ int cur[256];
    __shared__ uint2 ed[KA_EPB];   // 20 KB
    const int t = threadIdx.x;

    // local exclusive scan of phist -> per-thread pexcl
    int pv = (t < NPART) ? phist[t] : 0;
    pb[t] = pv;
    h[t] = 0;
    __syncthreads();
    for (int off = 1; off < 256; off <<= 1) {
        int a = (t >= off) ? pb[t - off] : 0;
        __syncthreads();
        pb[t] += a;
        __syncthreads();
    }
    const int pexcl = pb[t] - pv;

    const int base = blockIdx.x * KA_EPB;
    int   ps[KA_ITER];
    uint2 es[KA_ITER];
#pragma unroll
    for (int k = 0; k < KA_ITER; ++k) {
        int e = base + k * 256 + t;
        int s = src[e], d = dst[e];
        es[k] = make_uint2((unsigned)s, (unsigned)d);
        ps[k] = d >> PBITS;
        atomicAdd(&h[ps[k]], 1);
    }
    __syncthreads();
    int v = h[t];
    lbase[t] = v;
    __syncthreads();
    for (int off = 1; off < 256; off <<= 1) {
        int a = (t >= off) ? lbase[t - off] : 0;
        __syncthreads();
        lbase[t] += a;
        __syncthreads();
    }
    int excl = lbase[t] - v;
    lbase[t] = excl;            // own slot only
    cur[t]   = excl;
    if (t < NPART && v > 0) gbase[t] = pexcl + atomicAdd(&gcur[t], v);
    __syncthreads();
    // scatter into LDS sorted by partition
#pragma unroll
    for (int k = 0; k < KA_ITER; ++k) {
        int pos = atomicAdd(&cur[ps[k]], 1);
        ed[pos] = es[k];
    }
    __syncthreads();
    // coalesced write-out (runs per partition)
    for (int i = t; i < KA_EPB; i += 256) {
        uint2 e2 = ed[i];
        int p = (int)(e2.y >> PBITS);
        epart[gbase[p] + (i - lbase[p])] = e2;
    }
}

// ---------------- K_d: per-partition local CSR -----------------------------
// One block per partition; recomputes partition base locally from phist.
__global__ __launch_bounds__(256) void local_csr_kernel(const uint2* __restrict__ epart,
                                                        const int* __restrict__ phist,
                                                        int2* __restrict__ ofs2,
                                                        int* __restrict__ srcs) {
    __shared__ int cnt[PSIZE];
    __shared__ int cur[PSIZE];
    __shared__ int scantmp[256];
    __shared__ int stage[STAGE_CAP];   // 16 KB
    __shared__ int ebs, ecs;
    const int p = blockIdx.x;
    const int t = threadIdx.x;

    // local exclusive scan of phist to find this partition's range
    int pv = (t < NPART) ? phist[t] : 0;
    scantmp[t] = pv;
    __syncthreads();
    for (int off = 1; off < 256; off <<= 1) {
        int a = (t >= off) ? scantmp[t - off] : 0;
        __syncthreads();
        scantmp[t] += a;
        __syncthreads();
    }
    if (t == p) { ebs = scantmp[t] - pv; ecs = pv; }
    cnt[t] = 0; cnt[t + 256] = 0;
    __syncthreads();
    const int eb = ebs;
    const int ecount = ecs;

    for (int i = t; i < ecount; i += 256) {
        int nid = (int)epart[eb + i].y - (p << PBITS);
        atomicAdd(&cnt[nid], 1);
    }
    __syncthreads();
    // scan 512 (thread owns 2 consecutive)
    int c0 = cnt[2 * t], c1 = cnt[2 * t + 1];
    int pair = c0 + c1;
    scantmp[t] = pair;
    __syncthreads();
    for (int off = 1; off < 256; off <<= 1) {
        int a = (t >= off) ? scantmp[t - off] : 0;
        __syncthreads();
        scantmp[t] += a;
        __syncthreads();
    }
    int pexcl = scantmp[t] - pair;
    cur[2 * t]     = pexcl;
    cur[2 * t + 1] = pexcl + c0;
    int n0 = (p << PBITS) + 2 * t;
    if (n0 < NN)     ofs2[n0]     = make_int2(eb + pexcl,      eb + pexcl + c0);
    if (n0 + 1 < NN) ofs2[n0 + 1] = make_int2(eb + pexcl + c0, eb + pexcl + c0 + c1);
    __syncthreads();
    // pass 2: scatter srcs via LDS stage
    for (int i = t; i < ecount; i += 256) {
        uint2 e2 = epart[eb + i];
        int nid = (int)e2.y - (p << PBITS);
        int slot = atomicAdd(&cur[nid], 1);
        if (slot < STAGE_CAP) stage[slot] = (int)e2.x;
        else srcs[eb + slot] = (int)e2.x;   // overflow fallback (won't trigger)
    }
    __syncthreads();
    int lim = (ecount < STAGE_CAP) ? ecount : STAGE_CAP;
    for (int i = t; i < lim; i += 256) srcs[eb + i] = stage[i];
}

// ---------------- gather-mean, 128-dim fp8 in -> bf16 out ------------------
// 2 nodes per wave: each 32-lane half owns one node; lane holds 4 fp8 dims.
__global__ __launch_bounds__(256) void gather_mean_fp8_kernel(const unsigned char* __restrict__ xq,
                                                              const int2* __restrict__ ofs2,
                                                              const int* __restrict__ srcs,
                                                              unsigned short* __restrict__ agg) {
    const int gid    = blockIdx.x * 256 + threadIdx.x;
    const int node   = gid >> 5;               // 2 nodes per wave
    const int lane32 = threadIdx.x & 31;
    if (node >= NN) return;
    const int2 be = ofs2[node];
    const int b = be.x;
    const int e = be.y;
    const unsigned char* fp = xq + lane32 * 4;

    float a0 = 0.f, a1 = 0.f, a2 = 0.f, a3 = 0.f;
    float c0 = 0.f, c1 = 0.f, c2 = 0.f, c3 = 0.f;

    for (int j = b; j < e; j += 8) {
        int s[8];
#pragma unroll
        for (int k = 0; k < 8; ++k)
            s[k] = (j + k < e) ? srcs[j + k] : -1;
        unsigned int v[8];
#pragma unroll
        for (int k = 0; k < 8; ++k)
            v[k] = ((unsigned)s[k] < (unsigned)NN)
                 ? *reinterpret_cast<const unsigned int*>(fp + (size_t)s[k] * DF) : 0u;
        float x0, y0, x1, y1;
        fp8quad(v[0], x0, y0, x1, y1); a0 += x0; a1 += y0; a2 += x1; a3 += y1;
        fp8quad(v[1], x0, y0, x1, y1); c0 += x0; c1 += y0; c2 += x1; c3 += y1;
        fp8quad(v[2], x0, y0, x1, y1); a0 += x0; a1 += y0; a2 += x1; a3 += y1;
        fp8quad(v[3], x0, y0, x1, y1); c0 += x0; c1 += y0; c2 += x1; c3 += y1;
        fp8quad(v[4], x0, y0, x1, y1); a0 += x0; a1 += y0; a2 += x1; a3 += y1;
        fp8quad(v[5], x0, y0, x1, y1); c0 += x0; c1 += y0; c2 += x1; c3 += y1;
        fp8quad(v[6], x0, y0, x1, y1); a0 += x0; a1 += y0; a2 += x1; a3 += y1;
        fp8quad(v[7], x0, y0, x1, y1); c0 += x0; c1 += y0; c2 += x1; c3 += y1;
    }

    const float sc = 1.0f / fmaxf((float)(e - b), 1.0f);
    float s0 = (a0 + c0) * sc, s1 = (a1 + c1) * sc;
    float s2 = (a2 + c2) * sc, s3 = (a3 + c3) * sc;
    uint2 o;
    o.x = (unsigned)f2bf(s0) | ((unsigned)f2bf(s1) << 16);
    o.y = (unsigned)f2bf(s2) | ((unsigned)f2bf(s3) << 16);
    *reinterpret_cast<uint2*>(agg + (size_t)node * DF + lane32 * 4) = o;
}

// ---------------- MFMA GEMM (layer 1 + both layer-2 projections) -----------
// A-frag: lane holds A[row = lane&15][k = (lane>>4)*8 + j]
#define G_ROWS 64
#define LDSW 136

__global__ __launch_bounds__(256) void gemm1_kernel(const unsigned short* __restrict__ aggb,
                                                    const unsigned short* __restrict__ xb,
                                                    const unsigned short* __restrict__ w1p,
                                                    const unsigned short* __restrict__ w2lp,
                                                    const unsigned short* __restrict__ w2rp,
                                                    const float* __restrict__ b1,
                                                    const float* __restrict__ b2,
                                                    unsigned short* __restrict__ h2b,
                                                    unsigned short* __restrict__ h2rb) {
    __shared__ unsigned short sA[G_ROWS * LDSW];
    __shared__ unsigned short sX[G_ROWS * LDSW];
    const int t = threadIdx.x;
    const int row0 = blockIdx.x * G_ROWS;

    for (int i = t; i < G_ROWS * 16; i += 256) {
        int r = i >> 4, ch = i & 15;
        int sr = row0 + r; if (sr > NN - 1) sr = NN - 1;
        *reinterpret_cast<uint4*>(&sA[r * LDSW + ch * 8]) =
            *reinterpret_cast<const uint4*>(aggb + (size_t)sr * DF + ch * 8);
        *reinterpret_cast<uint4*>(&sX[r * LDSW + ch * 8]) =
            *reinterpret_cast<const uint4*>(xb + (size_t)sr * DF + ch * 8);
    }
    __syncthreads();

    const int lane = t & 63;
    const int w = t >> 6;
    const int lr = lane & 15;
    const int hi = lane >> 4;
    f32x4 acc[8];
#pragma unroll
    for (int i = 0; i < 8; ++i) acc[i] = (f32x4){0.f, 0.f, 0.f, 0.f};

    const int arow = (w * 16 + lr) * LDSW + hi * 8;
#pragma unroll
    for (int half = 0; half < 2; ++half) {
        const unsigned short* base = half ? sX : sA;
#pragma unroll
        for (int kq = 0; kq < 4; ++kq) {
            bf16x8 a = __builtin_bit_cast(bf16x8,
                *reinterpret_cast<const uint4*>(&base[arow + kq * 32]));
            const unsigned short* wp = w1p + (size_t)(((half * 4 + kq) * 8) * 64 + lane) * 8;
#pragma unroll
            for (int ct = 0; ct < 8; ++ct) {
                bf16x8 b = __builtin_bit_cast(bf16x8,
                    *reinterpret_cast<const uint4*>(wp + ct * 512));
                acc[ct] = __builtin_amdgcn_mfma_f32_16x16x32_bf16(a, b, acc[ct], 0, 0, 0);
            }
        }
    }

    // relu + bias -> bf16 registers
    unsigned short hreg[8][4];
#pragma unroll
    for (int ct = 0; ct < 8; ++ct) {
        float bias = b1[ct * 16 + lr];
#pragma unroll
        for (int v = 0; v < 4; ++v) {
            hreg[ct][v] = f2bf(fmaxf(acc[ct][v] + bias, 0.f));
        }
    }

    __syncthreads();   // stage-1 LDS reads done before overwrite
#pragma unroll
    for (int ct = 0; ct < 8; ++ct) {
#pragma unroll
        for (int v = 0; v < 4; ++v) {
            sA[(w * 16 + hi * 4 + v) * LDSW + ct * 16 + lr] = hreg[ct][v];
        }
    }
    __syncthreads();

    // stages 2+3: h @ W2l and h @ W2r + b2 (48 padded cols each)
    f32x4 acc2[3], acc3[3];
#pragma unroll
    for (int i = 0; i < 3; ++i) {
        acc2[i] = (f32x4){0.f, 0.f, 0.f, 0.f};
        acc3[i] = (f32x4){0.f, 0.f, 0.f, 0.f};
    }
#pragma unroll
    for (int kq = 0; kq < 4; ++kq) {
        bf16x8 a = __builtin_bit_cast(bf16x8,
            *reinterpret_cast<const uint4*>(&sA[arow + kq * 32]));
        const unsigned short* wpl = w2lp + (size_t)((kq * 3) * 64 + lane) * 8;
        const unsigned short* wpr = w2rp + (size_t)((kq * 3) * 64 + lane) * 8;
#pragma unroll
        for (int ct = 0; ct < 3; ++ct) {
            bf16x8 bl = __builtin_bit_cast(bf16x8,
                *reinterpret_cast<const uint4*>(wpl + ct * 512));
            bf16x8 br = __builtin_bit_cast(bf16x8,
                *reinterpret_cast<const uint4*>(wpr + ct * 512));
            acc2[ct] = __builtin_amdgcn_mfma_f32_16x16x32_bf16(a, bl, acc2[ct], 0, 0, 0);
            acc3[ct] = __builtin_amdgcn_mfma_f32_16x16x32_bf16(a, br, acc3[ct], 0, 0, 0);
        }
    }
#pragma unroll
    for (int ct = 0; ct < 3; ++ct) {
        int col = ct * 16 + lr;
        float bias2 = (col < DOUT) ? b2[col] : 0.f;
#pragma unroll
        for (int v = 0; v < 4; ++v) {
            int row = row0 + w * 16 + hi * 4 + v;
            if (row < NN) {
                h2b[(size_t)row * D2 + col]  = f2bf(acc2[ct][v]);
                h2rb[(size_t)row * D2 + col] = f2bf(acc3[ct][v] + bias2);
            }
        }
    }
}

// ---------------- fused gather48 + log_softmax, 2 nodes per wave -----------
__global__ __launch_bounds__(256) void gather_finish_kernel(const unsigned short* __restrict__ h2b,
                                                            const unsigned short* __restrict__ h2rb,
                                                            const int2* __restrict__ ofs2,
                                                            const int* __restrict__ srcs,
                                                            float* __restrict__ out) {
    const int gid   = blockIdx.x * 256 + threadIdx.x;
    const int node  = gid >> 5;                 // 2 nodes per wave
    const int lane32 = threadIdx.x & 31;
    if (node >= NN) return;
    const int2 be = ofs2[node];
    const int b = be.x;
    const int e = be.y;
    const bool act = lane32 < 20;
    const unsigned short* fp = h2b + lane32 * 2;

    float ax0 = 0.f, ay0 = 0.f, ax1 = 0.f, ay1 = 0.f;
    float ax2 = 0.f, ay2 = 0.f, ax3 = 0.f, ay3 = 0.f;

    for (int j = b; j < e; j += 8) {
        int s[8];
#pragma unroll
        for (int k = 0; k < 8; ++k)
            s[k] = (j + k < e) ? srcs[j + k] : -1;
        unsigned int v[8];
#pragma unroll
        for (int k = 0; k < 8; ++k)
            v[k] = (act && (unsigned)s[k] < (unsigned)NN)
                 ? *reinterpret_cast<const unsigned int*>(fp + (size_t)s[k] * D2) : 0u;
        ax0 += __uint_as_float(v[0] << 16);  ay0 += __uint_as_float(v[0] & 0xffff0000u);
        ax1 += __uint_as_float(v[1] << 16);  ay1 += __uint_as_float(v[1] & 0xffff0000u);
        ax2 += __uint_as_float(v[2] << 16);  ay2 += __uint_as_float(v[2] & 0xffff0000u);
        ax3 += __uint_as_float(v[3] << 16);  ay3 += __uint_as_float(v[3] & 0xffff0000u);
        ax0 += __uint_as_float(v[4] << 16);  ay0 += __uint_as_float(v[4] & 0xffff0000u);
        ax1 += __uint_as_float(v[5] << 16);  ay1 += __uint_as_float(v[5] & 0xffff0000u);
        ax2 += __uint_as_float(v[6] << 16);  ay2 += __uint_as_float(v[6] & 0xffff0000u);
        ax3 += __uint_as_float(v[7] << 16);  ay3 += __uint_as_float(v[7] & 0xffff0000u);
    }

    const float sc = 1.0f / fmaxf((float)(e - b), 1.0f);
    float a0 = ((ax0 + ax1) + (ax2 + ax3)) * sc;
    float a1 = ((ay0 + ay1) + (ay2 + ay3)) * sc;

    float lv0 = -INFINITY, lv1 = -INFINITY;
    if (act) {
        unsigned int sv = *reinterpret_cast<const unsigned int*>(h2rb + (size_t)node * D2 + lane32 * 2);
        lv0 = a0 + __uint_as_float(sv << 16);
        lv1 = a1 + __uint_as_float(sv & 0xffff0000u);
    }

    float mx = fmaxf(lv0, lv1);
#pragma unroll
    for (int off = 16; off > 0; off >>= 1) mx = fmaxf(mx, __shfl_xor(mx, off));
    float e0 = act ? __expf(lv0 - mx) : 0.f;
    float e1 = act ? __expf(lv1 - mx) : 0.f;
    float s = e0 + e1;
#pragma unroll
    for (int off = 16; off > 0; off >>= 1) s += __shfl_xor(s, off);
    float lz = mx + __logf(s);
    if (act) {
        float2 o = make_float2(lv0 - lz, lv1 - lz);
        *reinterpret_cast<float2*>(out + (size_t)node * DOUT + lane32 * 2) = o;
    }
}

extern "C" void kernel_launch(void* const* d_in, const int* in_sizes, int n_in,
                              void* d_out, int out_size, void* d_ws, size_t ws_size,
                              hipStream_t stream) {
    const float* x   = (const float*)d_in[0];
    const int*   ei  = (const int*)d_in[1];
    const int*   src = ei;
    const int*   dst = ei + NE;
    const float* W1l = (const float*)d_in[2];
    const float* W1r = (const float*)d_in[3];
    const float* b1  = (const float*)d_in[4];
    const float* W2l = (const float*)d_in[5];
    const float* W2r = (const float*)d_in[6];
    const float* b2  = (const float*)d_in[7];
    float* out = (float*)d_out;

    int* ip     = (int*)d_ws;
    int* phist  = ip;                 // 256
    int* gcur   = ip + 256;           // 256
    int* srcs   = ip + 512;           // 640008
    uint2* epart = (uint2*)(ip + 640520);       // NE uint2 = 1,280,000 ints
    int2*  ofs2  = (int2*)(ip + 1920520);       // NN int2  =   200,000 ints
    unsigned short* up    = (unsigned short*)(ip + 2120520);  // 8B aligned
    unsigned short* xb    = up;                   // NN*DF = 12,800,000
    unsigned short* aggb  = up + 12800000;        // NN*DF
    unsigned short* h2b   = up + 25600000;        // NN*48 = 4,800,000
    unsigned short* h2rb  = up + 30400000;        // NN*48
    unsigned short* w1p   = up + 35200000;        // 32768
    unsigned short* w2lp  = up + 35232768;        // 6144
    unsigned short* w2rp  = up + 35238912;        // 6144
    unsigned char*  xq    = (unsigned char*)(up + 35245056);  // NN*DF bytes

    mega_kernel<<<MK_GRID, 256, 0, stream>>>(x, xb, xq, W1l, W1r, w1p,
                                             W2l, W2r, w2lp, w2rp, phist, gcur);

    part_hist_kernel<<<KA_BLOCKS, 256, 0, stream>>>(dst, phist);
    part_scatter_kernel<<<KA_BLOCKS, 256, 0, stream>>>(src, dst, phist, gcur, epart);
    local_csr_kernel<<<NPART, 256, 0, stream>>>(epart, phist, ofs2, srcs);

    gather_mean_fp8_kernel<<<12500, 256, 0, stream>>>(xq, ofs2, srcs, aggb);
    gemm1_kernel<<<1563, 256, 0, stream>>>(aggb, xb, w1p, w2lp, w2rp, b1, b2, h2b, h2rb);
    gather_finish_kernel<<<12500, 256, 0, stream>>>(h2b, h2rb, ofs2, srcs, out);
}